// Round 1
// baseline (1985.047 us; speedup 1.0000x reference)
//
#include <hip/hip_runtime.h>
#include <math.h>

#define N_NODES 16384
#define N_EDGES 131072
#define N_MOLS 512
#define HDIM 256
#define NLAYER 3
#define NRBF 50
#define RSTR 52
#define CUT 5.0f
#define HH (HDIM*HDIM)

__device__ __forceinline__ float softplusf(float x){ return fmaxf(x,0.f)+log1pf(expf(-fabsf(x))); }
__device__ __forceinline__ float siluf(float x){ return x/(1.f+expf(-x)); }

// ---------------- CSR build ----------------
__global__ void k_hist(const int* __restrict__ dst, int* __restrict__ cnt){
  int e = blockIdx.x*256 + threadIdx.x;
  if(e < N_EDGES) atomicAdd(&cnt[dst[e]], 1);
}

__global__ __launch_bounds__(1024) void k_scan(const int* __restrict__ cnt,
                                               int* __restrict__ rowptr,
                                               int* __restrict__ cursor){
  __shared__ int part[1024];
  int tid = threadIdx.x;
  int base = tid*16;
  int loc[16]; int s=0;
  #pragma unroll
  for(int i=0;i<16;i++){ loc[i]=s; s+=cnt[base+i]; }
  part[tid]=s; __syncthreads();
  for(int off=1; off<1024; off<<=1){
    int v = (tid>=off)? part[tid-off] : 0;
    __syncthreads();
    part[tid] += v;
    __syncthreads();
  }
  int pre = (tid==0)?0:part[tid-1];
  #pragma unroll
  for(int i=0;i<16;i++){ int v = pre+loc[i]; rowptr[base+i]=v; cursor[base+i]=v; }
  if(tid==1023) rowptr[N_NODES]=part[1023];
}

__global__ void k_scatter(const int* __restrict__ dst, int* __restrict__ cursor,
                          int* __restrict__ perm){
  int e = blockIdx.x*256+threadIdx.x;
  if(e<N_EDGES){ int p = atomicAdd(&cursor[dst[e]],1); perm[p]=e; }
}

// ---------------- RBF ----------------
__global__ void k_rbf(const float* __restrict__ dist, float* __restrict__ rbf){
  int gid = blockIdx.x*256+threadIdx.x;
  int e = gid>>6, r = gid&63;
  if(r>=RSTR) return;
  if(r>=NRBF){ rbf[(size_t)e*RSTR+r]=0.f; return; }
  float d = dist[e];
  float env = 0.5f*(cosf(3.14159265358979f*d/CUT)+1.f) * (d<CUT ? 1.f:0.f);
  float c = CUT*(float)r/(float)(NRBF-1);
  float u = (d - c)/(CUT/(float)NRBF);
  rbf[(size_t)e*RSTR+r] = expf(-0.5f*u*u)*env;
}

// ---------------- embedding ----------------
__global__ void k_embed(const float* __restrict__ at, const float* __restrict__ co,
                        const float* __restrict__ Wm, const float* __restrict__ bm,
                        const float* __restrict__ Wp, const float* __restrict__ bp,
                        float* __restrict__ mag, float* __restrict__ ph){
  int n = blockIdx.x; int h = threadIdx.x;
  __shared__ float x[8];
  if(threadIdx.x<5) x[threadIdx.x] = at[n*5+threadIdx.x];
  else if(threadIdx.x<8) x[threadIdx.x] = co[n*3+threadIdx.x-5];
  __syncthreads();
  float tm=bm[h], tp=bp[h];
  #pragma unroll
  for(int i=0;i<8;i++){ tm = fmaf(x[i],Wm[i*HDIM+h],tm); tp = fmaf(x[i],Wp[i*HDIM+h],tp); }
  mag[(size_t)n*HDIM+h] = softplusf(tm);
  ph[(size_t)n*HDIM+h] = 3.14159265358979f*tanhf(tp);
}

// ---------------- f32 SGEMM: C[M,256] (+)= A[M,256] @ W[256,256] (+bias) ----------------
template<int ACCUM,int BIAS>
__global__ __launch_bounds__(256) void k_sgemm(const float* __restrict__ A,
                                               const float* __restrict__ W,
                                               const float* __restrict__ bias,
                                               float* __restrict__ C){
  __shared__ float As[16][64];
  __shared__ float Bs[16][64];
  int tid = threadIdx.x;
  int tx = tid & 15, ty = tid >> 4;
  int n0 = blockIdx.x*64;
  int m0 = blockIdx.y*64;
  float acc[4][4] = {};
  int ar = tid>>2, ak = (tid&3)*4;
  int bk = tid>>4, bn = (tid&15)*4;
  const int K = HDIM;
  for(int k0=0;k0<K;k0+=16){
    float4 a4 = *(const float4*)(A + (size_t)(m0+ar)*K + k0 + ak);
    As[ak+0][ar]=a4.x; As[ak+1][ar]=a4.y; As[ak+2][ar]=a4.z; As[ak+3][ar]=a4.w;
    *(float4*)&Bs[bk][bn] = *(const float4*)(W + (size_t)(k0+bk)*HDIM + n0 + bn);
    __syncthreads();
    #pragma unroll
    for(int k=0;k<16;k++){
      float4 av = *(const float4*)&As[k][ty*4];
      float4 bv = *(const float4*)&Bs[k][tx*4];
      float am[4]={av.x,av.y,av.z,av.w};
      float bm_[4]={bv.x,bv.y,bv.z,bv.w};
      #pragma unroll
      for(int i=0;i<4;i++)
        #pragma unroll
        for(int j=0;j<4;j++) acc[i][j] = fmaf(am[i],bm_[j],acc[i][j]);
    }
    __syncthreads();
  }
  float4 bb = {0.f,0.f,0.f,0.f};
  if(BIAS) bb = *(const float4*)(bias + n0 + tx*4);
  #pragma unroll
  for(int i=0;i<4;i++){
    float* cp = C + (size_t)(m0+ty*4+i)*HDIM + n0 + tx*4;
    float4 v;
    v.x = acc[i][0]+bb.x; v.y=acc[i][1]+bb.y; v.z=acc[i][2]+bb.z; v.w=acc[i][3]+bb.w;
    if(ACCUM){ float4 o = *(const float4*)cp; v.x+=o.x; v.y+=o.y; v.z+=o.z; v.w+=o.w; }
    *(float4*)cp = v;
  }
}

// ---------------- attention score ----------------
__global__ __launch_bounds__(256) void k_score(const float* __restrict__ qm, const float* __restrict__ km,
                        const float* __restrict__ qp, const float* __restrict__ kp,
                        const float* __restrict__ rbf, const float* __restrict__ We,
                        const float* __restrict__ be,
                        const int* __restrict__ src, const int* __restrict__ dstA,
                        float* __restrict__ score){
  int w = threadIdx.x>>6, lane = threadIdx.x&63;
  int e = blockIdx.x*4 + w;
  int s = src[e], d = dstA[e];
  float p = 0.f;
  #pragma unroll
  for(int j=0;j<4;j++){
    int h = lane + j*64;
    float dphi = qp[d*HDIM+h]-kp[s*HDIM+h];
    p = fmaf(qm[d*HDIM+h]*km[s*HDIM+h], cosf(dphi), p);
  }
  p *= 0.0625f; // 1/sqrt(256)
  if(lane<NRBF) p = fmaf(rbf[(size_t)e*RSTR+lane], We[lane], p);
  #pragma unroll
  for(int off=32; off; off>>=1) p += __shfl_down(p, off, 64);
  if(lane==0) score[e] = p + be[0];
}

// ---------------- segment softmax over dst (CSR) ----------------
__global__ void k_segsoftmax(const int* __restrict__ rowptr, const int* __restrict__ perm,
                             float* __restrict__ score){
  int n = blockIdx.x*256+threadIdx.x;
  if(n>=N_NODES) return;
  int b = rowptr[n], e = rowptr[n+1];
  float m = -3.4e38f;
  for(int i=b;i<e;i++) m = fmaxf(m, score[perm[i]]);
  float z = 0.f;
  for(int i=b;i<e;i++) z += expf(score[perm[i]]-m);
  float inv = 1.f/(z+1e-9f);
  for(int i=b;i<e;i++){ int ed=perm[i]; score[ed] = expf(score[ed]-m)*inv; }
}

// ---------------- attention aggregation ----------------
__global__ __launch_bounds__(256) void k_attn_agg(const int* __restrict__ rowptr, const int* __restrict__ perm,
                           const int* __restrict__ src, const float* __restrict__ alpha,
                           const float* __restrict__ vm, const float* __restrict__ vp,
                           float* __restrict__ nmag, float* __restrict__ nph){
  int n = blockIdx.x; int h = threadIdx.x;
  int b = rowptr[n], e = rowptr[n+1];
  float am=0.f, ap=0.f;
  for(int i=b;i<e;i++){
    int ed = perm[i]; int s = src[ed]; float a = alpha[ed];
    am = fmaf(a, vm[(size_t)s*HDIM+h], am);
    ap = fmaf(a, vp[(size_t)s*HDIM+h], ap);
  }
  nmag[(size_t)n*HDIM+h]=am; nph[(size_t)n*HDIM+h]=ap;
}

// ---------------- message passing aggregation (gate on the fly) ----------------
#define NPB 16
__global__ __launch_bounds__(256) void k_mp_agg(const int* __restrict__ rowptr, const int* __restrict__ perm,
                         const int* __restrict__ src, const float* __restrict__ rbf,
                         const float* __restrict__ We, const float* __restrict__ be,
                         const float* __restrict__ nmag, const float* __restrict__ nph,
                         float* __restrict__ aggm, float* __restrict__ aggp){
  int tid = threadIdx.x;
  float w[RSTR];
  #pragma unroll
  for(int r=0;r<NRBF;r++) w[r] = We[r*HDIM+tid];
  w[50]=0.f; w[51]=0.f;
  float sb = be[tid];
  for(int nn=0; nn<NPB; nn++){
    int n = blockIdx.x*NPB+nn;
    int b = rowptr[n], e = rowptr[n+1];
    float am=0.f, ap=0.f;
    for(int i=b;i<e;i++){
      int ed=perm[i]; int s=src[ed];
      const float* rr = rbf + (size_t)ed*RSTR;
      float g = sb;
      #pragma unroll
      for(int r4=0;r4<13;r4++){
        float4 rv = *(const float4*)(rr + r4*4);
        g = fmaf(rv.x, w[r4*4+0], g);
        g = fmaf(rv.y, w[r4*4+1], g);
        g = fmaf(rv.z, w[r4*4+2], g);
        g = fmaf(rv.w, w[r4*4+3], g);
      }
      g = siluf(g);
      am = fmaf(g, nmag[(size_t)s*HDIM+tid], am);
      ap = fmaf(g, nph[(size_t)s*HDIM+tid], ap);
    }
    aggm[(size_t)n*HDIM+tid]=am; aggp[(size_t)n*HDIM+tid]=ap;
  }
}

// ---------------- residual + LayerNorm ----------------
__global__ __launch_bounds__(256) void k_resid_ln(const float* __restrict__ nmag, const float* __restrict__ nph,
                           float* __restrict__ mag, float* __restrict__ ph,
                           const float* __restrict__ g, const float* __restrict__ b){
  int n = blockIdx.x, tid = threadIdx.x;
  size_t idx = (size_t)n*HDIM+tid;
  float t = nmag[idx] + mag[idx];
  float s1=t, s2=t*t;
  #pragma unroll
  for(int off=32; off; off>>=1){ s1 += __shfl_down(s1,off,64); s2 += __shfl_down(s2,off,64); }
  __shared__ float w1[4], w2[4], bc[2];
  int wid = tid>>6, lane = tid&63;
  if(lane==0){ w1[wid]=s1; w2[wid]=s2; }
  __syncthreads();
  if(tid==0){
    float a=w1[0]+w1[1]+w1[2]+w1[3];
    float q=w2[0]+w2[1]+w2[2]+w2[3];
    float mu = a*(1.f/HDIM);
    float var = q*(1.f/HDIM) - mu*mu;
    bc[0]=mu; bc[1]=rsqrtf(var+1e-5f);
  }
  __syncthreads();
  float mu=bc[0], rs=bc[1];
  mag[idx] = (t-mu)*rs*g[tid]+b[tid];
  ph[idx] = nph[idx] + ph[idx];
}

// ---------------- projection input ----------------
__global__ void k_tcos(const float* __restrict__ mag, const float* __restrict__ ph,
                       float* __restrict__ t){
  size_t i = (size_t)blockIdx.x*256+threadIdx.x;
  t[i] = mag[i]*cosf(ph[i]);
}

// ---------------- pooling ----------------
__global__ void k_pool(const float* __restrict__ arepr, const int* __restrict__ n2m,
                       float* __restrict__ spool, float* __restrict__ cntf){
  int gid = blockIdx.x*256+threadIdx.x;
  int n = gid>>8, h = gid&255;
  int m = n2m[n];
  atomicAdd(&spool[(size_t)m*HDIM+h], arepr[(size_t)n*HDIM+h]);
  if(h==0) atomicAdd(&cntf[m], 1.f);
}

// ---------------- head MLP ----------------
__global__ __launch_bounds__(256) void k_head(const float* __restrict__ spool, const float* __restrict__ cntf,
                       const float* __restrict__ W1, const float* __restrict__ b1,
                       const float* __restrict__ W2, const float* __restrict__ b2,
                       const float* __restrict__ W3, const float* __restrict__ b3,
                       float* __restrict__ out){
  __shared__ float smol[2*HDIM];
  __shared__ float sh1[HDIM];
  __shared__ float sh2[HDIM/2];
  int m = blockIdx.x, tid = threadIdx.x;
  float sv = spool[(size_t)m*HDIM+tid];
  float c = cntf[m];
  smol[tid] = sv/fmaxf(c,1.f);
  smol[HDIM+tid] = sv;
  __syncthreads();
  float a = b1[tid];
  for(int i=0;i<2*HDIM;i++) a = fmaf(smol[i], W1[i*HDIM+tid], a);
  sh1[tid] = siluf(a);
  __syncthreads();
  if(tid<128){
    float a2 = b2[tid];
    for(int i=0;i<HDIM;i++) a2 = fmaf(sh1[i], W2[i*128+tid], a2);
    sh2[tid] = siluf(a2);
  }
  __syncthreads();
  if(tid<64){
    float p = sh2[tid]*W3[tid] + sh2[tid+64]*W3[tid+64];
    #pragma unroll
    for(int off=32; off; off>>=1) p += __shfl_down(p,off,64);
    if(tid==0) out[m] = p + b3[0];
  }
}

extern "C" void kernel_launch(void* const* d_in, const int* in_sizes, int n_in,
                              void* d_out, int out_size, void* d_ws, size_t ws_size,
                              hipStream_t stream){
  const float* atom_types = (const float*)d_in[0];
  const float* coords     = (const float*)d_in[1];
  const float* edge_dist  = (const float*)d_in[2];
  const int*   edge_index = (const int*)d_in[3];
  const int*   node2mol   = (const int*)d_in[4];
  const float* emb_Wm = (const float*)d_in[5];
  const float* emb_bm = (const float*)d_in[6];
  const float* emb_Wp = (const float*)d_in[7];
  const float* emb_bp = (const float*)d_in[8];
  const float* attn_Wqm = (const float*)d_in[9];
  const float* attn_Wkm = (const float*)d_in[10];
  const float* attn_Wvm = (const float*)d_in[11];
  const float* attn_Wqp = (const float*)d_in[12];
  const float* attn_Wkp = (const float*)d_in[13];
  const float* attn_Wvp = (const float*)d_in[14];
  const float* attn_We  = (const float*)d_in[15];
  const float* attn_be  = (const float*)d_in[16];
  const float* mp_We = (const float*)d_in[17];
  const float* mp_be = (const float*)d_in[18];
  const float* mp_Wm = (const float*)d_in[19];
  const float* mp_bm = (const float*)d_in[20];
  const float* mp_Wp = (const float*)d_in[21];
  const float* mp_bp = (const float*)d_in[22];
  const float* ln_g = (const float*)d_in[23];
  const float* ln_b = (const float*)d_in[24];
  const float* proj_W = (const float*)d_in[25];
  const float* proj_b = (const float*)d_in[26];
  const float* head_W1 = (const float*)d_in[27];
  const float* head_b1 = (const float*)d_in[28];
  const float* head_W2 = (const float*)d_in[29];
  const float* head_b2 = (const float*)d_in[30];
  const float* head_W3 = (const float*)d_in[31];
  const float* head_b3 = (const float*)d_in[32];
  float* out = (float*)d_out;

  float* ws = (float*)d_ws;
  const size_t NH = (size_t)N_NODES*HDIM;
  size_t o = 0;
  float* rbf = ws + o; o += (size_t)N_EDGES*RSTR;
  float* mag = ws + o; o += NH;
  float* ph  = ws + o; o += NH;
  float* qm  = ws + o; o += NH;
  float* km  = ws + o; o += NH;
  float* vm  = ws + o; o += NH;
  float* qp  = ws + o; o += NH;
  float* kp  = ws + o; o += NH;
  float* vp  = ws + o; o += NH;
  float* nmag= ws + o; o += NH;
  float* nph = ws + o; o += NH;
  float* score = ws + o; o += N_EDGES;
  float* spool = ws + o; o += (size_t)N_MOLS*HDIM;
  float* cntf  = ws + o; o += N_MOLS;
  int* rowptr = (int*)(ws + o); o += N_NODES+1;
  int* cnt    = (int*)(ws + o); o += N_NODES;
  int* cursor = (int*)(ws + o); o += N_NODES;
  int* perm   = (int*)(ws + o); o += N_EDGES;
  // reuse after their last read:
  float* aggm = qm;
  float* aggp = km;
  float* tbuf = qp;
  float* arepr= kp;

  const int* src = edge_index;
  const int* dst = edge_index + N_EDGES;

  hipMemsetAsync(cnt, 0, N_NODES*sizeof(int), stream);
  k_hist<<<N_EDGES/256,256,0,stream>>>(dst, cnt);
  k_scan<<<1,1024,0,stream>>>(cnt, rowptr, cursor);
  k_scatter<<<N_EDGES/256,256,0,stream>>>(dst, cursor, perm);
  k_rbf<<<(N_EDGES*64)/256,256,0,stream>>>(edge_dist, rbf);
  k_embed<<<N_NODES,256,0,stream>>>(atom_types, coords, emb_Wm, emb_bm, emb_Wp, emb_bp, mag, ph);

  dim3 gg(HDIM/64, N_NODES/64);
  for(int l=0;l<NLAYER;l++){
    const float* Wqm = attn_Wqm + (size_t)l*HH;
    const float* Wkm = attn_Wkm + (size_t)l*HH;
    const float* Wvm = attn_Wvm + (size_t)l*HH;
    const float* Wqp = attn_Wqp + (size_t)l*HH;
    const float* Wkp = attn_Wkp + (size_t)l*HH;
    const float* Wvp = attn_Wvp + (size_t)l*HH;
    k_sgemm<0,0><<<gg,256,0,stream>>>(mag, Wqm, nullptr, qm);
    k_sgemm<0,0><<<gg,256,0,stream>>>(mag, Wkm, nullptr, km);
    k_sgemm<0,0><<<gg,256,0,stream>>>(mag, Wvm, nullptr, vm);
    k_sgemm<0,0><<<gg,256,0,stream>>>(ph,  Wqp, nullptr, qp);
    k_sgemm<0,0><<<gg,256,0,stream>>>(ph,  Wkp, nullptr, kp);
    k_sgemm<0,0><<<gg,256,0,stream>>>(ph,  Wvp, nullptr, vp);
    k_score<<<N_EDGES/4,256,0,stream>>>(qm,km,qp,kp,rbf, attn_We+(size_t)l*NRBF, attn_be+l, src, dst, score);
    k_segsoftmax<<<N_NODES/256,256,0,stream>>>(rowptr, perm, score);
    k_attn_agg<<<N_NODES,256,0,stream>>>(rowptr, perm, src, score, vm, vp, nmag, nph);
    k_mp_agg<<<N_NODES/NPB,256,0,stream>>>(rowptr, perm, src, rbf,
                                           mp_We+(size_t)l*NRBF*HDIM, mp_be+(size_t)l*HDIM,
                                           nmag, nph, aggm, aggp);
    k_sgemm<1,1><<<gg,256,0,stream>>>(aggm, mp_Wm+(size_t)l*HH, mp_bm+(size_t)l*HDIM, nmag);
    k_sgemm<1,1><<<gg,256,0,stream>>>(aggp, mp_Wp+(size_t)l*HH, mp_bp+(size_t)l*HDIM, nph);
    k_resid_ln<<<N_NODES,256,0,stream>>>(nmag, nph, mag, ph, ln_g+(size_t)l*HDIM, ln_b+(size_t)l*HDIM);
  }
  k_tcos<<<NH/256,256,0,stream>>>(mag, ph, tbuf);
  k_sgemm<0,1><<<gg,256,0,stream>>>(tbuf, proj_W, proj_b, arepr);
  hipMemsetAsync(spool, 0, ((size_t)N_MOLS*HDIM+N_MOLS)*sizeof(float), stream);
  k_pool<<<NH/256,256,0,stream>>>(arepr, node2mol, spool, cntf);
  k_head<<<N_MOLS,256,0,stream>>>(spool, cntf, head_W1, head_b1, head_W2, head_b2, head_W3, head_b3, out);
}

// Round 3
// 1233.497 us; speedup vs baseline: 1.6093x; 1.6093x over previous
//
#include <hip/hip_runtime.h>
#include <math.h>

#define N_NODES 16384
#define N_EDGES 131072
#define N_MOLS 512
#define HDIM 256
#define NLAYER 3
#define NRBF 50
#define CUT 5.0f
#define HH (HDIM*HDIM)

typedef unsigned short u16;
typedef __attribute__((ext_vector_type(8))) short short8v;
typedef __attribute__((ext_vector_type(4))) float f32x4;
typedef __attribute__((ext_vector_type(4))) unsigned short u16x4;

__device__ __forceinline__ float softplusf(float x){ return fmaxf(x,0.f)+log1pf(expf(-fabsf(x))); }
__device__ __forceinline__ float siluf(float x){ return x/(1.f+expf(-x)); }
__device__ __forceinline__ float bf2f(u16 u){ union{unsigned int i; float f;}v; v.i=((unsigned int)u)<<16; return v.f; }
__device__ __forceinline__ u16 f2bf(float f){ union{float f; unsigned int i;}v; v.f=f; unsigned int r = v.i + 0x7FFFu + ((v.i>>16)&1u); return (u16)(r>>16); }

__device__ __forceinline__ void gload_lds16(const void* g, void* l){
  __builtin_amdgcn_global_load_lds((const __attribute__((address_space(1))) unsigned int*)g,
                                   (__attribute__((address_space(3))) unsigned int*)l, 16, 0, 0);
}

// ---------------- CSR build ----------------
__global__ void k_hist(const int* __restrict__ dst, int* __restrict__ cnt){
  int e = blockIdx.x*256 + threadIdx.x;
  if(e < N_EDGES) atomicAdd(&cnt[dst[e]], 1);
}

__global__ __launch_bounds__(1024) void k_scan(const int* __restrict__ cnt,
                                               int* __restrict__ rowptr,
                                               int* __restrict__ cursor){
  __shared__ int part[1024];
  int tid = threadIdx.x;
  int base = tid*16;
  int loc[16]; int s=0;
  #pragma unroll
  for(int i=0;i<16;i++){ loc[i]=s; s+=cnt[base+i]; }
  part[tid]=s; __syncthreads();
  for(int off=1; off<1024; off<<=1){
    int v = (tid>=off)? part[tid-off] : 0;
    __syncthreads();
    part[tid] += v;
    __syncthreads();
  }
  int pre = (tid==0)?0:part[tid-1];
  #pragma unroll
  for(int i=0;i<16;i++){ int v = pre+loc[i]; rowptr[base+i]=v; cursor[base+i]=v; }
  if(tid==1023) rowptr[N_NODES]=part[1023];
}

__global__ void k_scatter(const int* __restrict__ dst, int* __restrict__ cursor,
                          int* __restrict__ perm){
  int e = blockIdx.x*256+threadIdx.x;
  if(e<N_EDGES){ int p = atomicAdd(&cursor[dst[e]],1); perm[p]=e; }
}

// ---------------- RBF (bf16, padded to 64) ----------------
__global__ void k_rbf(const float* __restrict__ dist, u16* __restrict__ rbf){
  int gid = blockIdx.x*256+threadIdx.x;
  int e = gid>>6, r = gid&63;
  u16 o = 0;
  if(r<NRBF){
    float d = dist[e];
    float env = 0.5f*(cosf(3.14159265358979f*d/CUT)+1.f) * (d<CUT ? 1.f:0.f);
    float c = CUT*(float)r/(float)(NRBF-1);
    float u = (d - c)/(CUT/(float)NRBF);
    o = f2bf(expf(-0.5f*u*u)*env);
  }
  rbf[(size_t)e*64+r] = o;
}

// ---------------- weight transpose+convert: W[K][256] f32 -> Wt[256][dK] bf16 ----------------
struct WDesc { const float* src; u16* dst; int K; int dK; };
struct WArgs { WDesc d[28]; };
__global__ __launch_bounds__(256) void k_wconv(WArgs a){
  WDesc w = a.d[blockIdx.x];
  int t = blockIdx.y;
  int ky = t >> 3, nx = t & 7;
  if(ky*32 >= w.dK) return;
  __shared__ float tile[32][33];
  int tid = threadIdx.x;
  int kk = tid >> 3, n4 = (tid & 7)*4;
  int k = ky*32 + kk;
  float4 v = {0.f,0.f,0.f,0.f};
  if(k < w.K) v = *(const float4*)(w.src + (size_t)k*HDIM + nx*32 + n4);
  tile[kk][n4+0]=v.x; tile[kk][n4+1]=v.y; tile[kk][n4+2]=v.z; tile[kk][n4+3]=v.w;
  __syncthreads();
  int nn = tid >> 3, k4 = (tid & 7)*4;
  u16x4 o;
  #pragma unroll
  for(int j=0;j<4;j++) o[j] = f2bf(tile[k4+j][nn]);
  *(u16x4*)(w.dst + (size_t)(nx*32+nn)*w.dK + ky*32 + k4) = o;
}

// ---------------- embedding ----------------
__global__ void k_embed(const float* __restrict__ at, const float* __restrict__ co,
                        const float* __restrict__ Wm, const float* __restrict__ bm,
                        const float* __restrict__ Wp, const float* __restrict__ bp,
                        float* __restrict__ mag, float* __restrict__ ph,
                        u16* __restrict__ magb, u16* __restrict__ phb){
  int n = blockIdx.x; int h = threadIdx.x;
  __shared__ float x[8];
  if(threadIdx.x<5) x[threadIdx.x] = at[n*5+threadIdx.x];
  else if(threadIdx.x<8) x[threadIdx.x] = co[n*3+threadIdx.x-5];
  __syncthreads();
  float tm=bm[h], tp=bp[h];
  #pragma unroll
  for(int i=0;i<8;i++){ tm = fmaf(x[i],Wm[i*HDIM+h],tm); tp = fmaf(x[i],Wp[i*HDIM+h],tp); }
  size_t idx = (size_t)n*HDIM+h;
  float m = softplusf(tm);
  float p = 3.14159265358979f*tanhf(tp);
  mag[idx]=m; ph[idx]=p; magb[idx]=f2bf(m); phb[idx]=f2bf(p);
}

// ---------------- MFMA GEMM body: C[M,256] = A[M,K]bf16 @ Bt[256,K]bf16^T ----------------
// BM=128, BN=64, BK=64; 256 threads = 4 waves in 2(M)x2(N); wave tile 64x32.
// MODE 0: bf16 out. 1: silu(x+bias)->bf16. 2: f32 += x+bias. 3: f32 = x+bias.
template<int MODE>
__device__ __forceinline__ void gemm_body(const u16* __restrict__ A,
                                          const u16* __restrict__ Bt,
                                          const float* __restrict__ bias,
                                          void* __restrict__ outp, int K){
  __shared__ __align__(16) u16 As[128*64];
  __shared__ __align__(16) u16 Bs[64*64];
  int tid = threadIdx.x;
  int lane = tid & 63, wid = tid >> 6;
  int wm = wid & 1, wn = wid >> 1;
  int m0 = blockIdx.y * 128;
  int n0 = blockIdx.x * 64;
  const size_t Kb = (size_t)K*2;
  f32x4 acc[4][2] = {};
  for(int k0=0; k0<K; k0+=64){
    #pragma unroll
    for(int it=0; it<4; it++){
      int off = it*4096 + tid*16;
      int row = off >> 7, col = off & 127;
      const char* g = (const char*)A + (size_t)(m0+row)*Kb + (size_t)k0*2 + col;
      gload_lds16(g, (char*)As + it*4096 + wid*1024);
    }
    #pragma unroll
    for(int it=0; it<2; it++){
      int off = it*4096 + tid*16;
      int row = off >> 7, col = off & 127;
      const char* g = (const char*)Bt + (size_t)(n0+row)*Kb + (size_t)k0*2 + col;
      gload_lds16(g, (char*)Bs + it*4096 + wid*1024);
    }
    __syncthreads();
    #pragma unroll
    for(int ks=0; ks<2; ks++){
      int kl = ks*32 + (lane>>4)*8;
      short8v a[4], b[2];
      #pragma unroll
      for(int fm=0; fm<4; fm++){
        int m = wm*64 + fm*16 + (lane&15);
        a[fm] = *(const short8v*)&As[m*64 + kl];
      }
      #pragma unroll
      for(int fn=0; fn<2; fn++){
        int n = wn*32 + fn*16 + (lane&15);
        b[fn] = *(const short8v*)&Bs[n*64 + kl];
      }
      #pragma unroll
      for(int fm=0; fm<4; fm++)
        #pragma unroll
        for(int fn=0; fn<2; fn++)
          acc[fm][fn] = __builtin_amdgcn_mfma_f32_16x16x32_bf16(a[fm], b[fn], acc[fm][fn], 0,0,0);
    }
    __syncthreads();
  }
  int ro = (lane>>4)*4, co = lane&15;
  #pragma unroll
  for(int fm=0; fm<4; fm++){
    #pragma unroll
    for(int fn=0; fn<2; fn++){
      int col = n0 + wn*32 + fn*16 + co;
      float bv = (MODE!=0) ? bias[col] : 0.f;
      #pragma unroll
      for(int r=0; r<4; r++){
        int row = m0 + wm*64 + fm*16 + ro + r;
        float v = acc[fm][fn][r] + bv;
        size_t ci = (size_t)row*HDIM + col;
        if(MODE==0) ((u16*)outp)[ci] = f2bf(v);
        else if(MODE==1) ((u16*)outp)[ci] = f2bf(siluf(v));
        else if(MODE==2) ((float*)outp)[ci] += v;
        else ((float*)outp)[ci] = v;
      }
    }
  }
}

struct QkvArgs { const u16* Wt[6]; u16* out[6]; };
__global__ __launch_bounds__(256,2) void k_gemm_qkv(const u16* __restrict__ magb,
                                                    const u16* __restrict__ phb, QkvArgs q){
  int z = blockIdx.z;
  const u16* A = (z<3) ? magb : phb;
  gemm_body<0>(A, q.Wt[z], nullptr, q.out[z], HDIM);
}
__global__ __launch_bounds__(256,2) void k_gemm_gate(const u16* __restrict__ rbfb,
                                                     const u16* __restrict__ Wt,
                                                     const float* __restrict__ be,
                                                     u16* __restrict__ gate){
  gemm_body<1>(rbfb, Wt, be, gate, 64);
}
__global__ __launch_bounds__(256,2) void k_gemm_mp(const u16* __restrict__ Ab,
                                                   const u16* __restrict__ Wt,
                                                   const float* __restrict__ b,
                                                   float* __restrict__ C){
  gemm_body<2>(Ab, Wt, b, C, HDIM);
}
__global__ __launch_bounds__(256,2) void k_gemm_proj(const u16* __restrict__ Ab,
                                                     const u16* __restrict__ Wt,
                                                     const float* __restrict__ b,
                                                     float* __restrict__ C){
  gemm_body<3>(Ab, Wt, b, C, HDIM);
}

// ---------------- attention score ----------------
__global__ __launch_bounds__(256) void k_score(const u16* __restrict__ qm, const u16* __restrict__ km,
                        const u16* __restrict__ qp, const u16* __restrict__ kp,
                        const u16* __restrict__ rbf, const float* __restrict__ We,
                        const float* __restrict__ be,
                        const int* __restrict__ src, const int* __restrict__ dstA,
                        float* __restrict__ score){
  int w = threadIdx.x>>6, lane = threadIdx.x&63;
  int e = blockIdx.x*4 + w;
  int s = src[e], d = dstA[e];
  u16x4 qmv = *(const u16x4*)(qm + (size_t)d*HDIM + lane*4);
  u16x4 kmv = *(const u16x4*)(km + (size_t)s*HDIM + lane*4);
  u16x4 qpv = *(const u16x4*)(qp + (size_t)d*HDIM + lane*4);
  u16x4 kpv = *(const u16x4*)(kp + (size_t)s*HDIM + lane*4);
  float p = 0.f;
  #pragma unroll
  for(int j=0;j<4;j++){
    float a = bf2f(qmv[j])*bf2f(kmv[j]);
    p = fmaf(a, cosf(bf2f(qpv[j])-bf2f(kpv[j])), p);
  }
  p *= 0.0625f;
  if(lane<NRBF) p = fmaf(bf2f(rbf[(size_t)e*64+lane]), We[lane], p);
  #pragma unroll
  for(int off=32; off; off>>=1) p += __shfl_down(p, off, 64);
  if(lane==0) score[e] = p + be[0];
}

// ---------------- segment softmax over dst (CSR) ----------------
__global__ void k_segsoftmax(const int* __restrict__ rowptr, const int* __restrict__ perm,
                             float* __restrict__ score){
  int n = blockIdx.x*256+threadIdx.x;
  if(n>=N_NODES) return;
  int b = rowptr[n], e = rowptr[n+1];
  float m = -3.4e38f;
  for(int i=b;i<e;i++) m = fmaxf(m, score[perm[i]]);
  float z = 0.f;
  for(int i=b;i<e;i++) z += expf(score[perm[i]]-m);
  float inv = 1.f/(z+1e-9f);
  for(int i=b;i<e;i++){ int ed=perm[i]; score[ed] = expf(score[ed]-m)*inv; }
}

// ---------------- attention aggregation (bf16 v) ----------------
__global__ __launch_bounds__(256) void k_attn_agg(const int* __restrict__ rowptr, const int* __restrict__ perm,
                           const int* __restrict__ src, const float* __restrict__ alpha,
                           const u16* __restrict__ vm, const u16* __restrict__ vp,
                           float* __restrict__ nmag, float* __restrict__ nph){
  int n = blockIdx.x; int h = threadIdx.x;
  int b = rowptr[n], e = rowptr[n+1];
  float am=0.f, ap=0.f;
  for(int i=b;i<e;i++){
    int ed = perm[i]; int s = src[ed]; float a = alpha[ed];
    am = fmaf(a, bf2f(vm[(size_t)s*HDIM+h]), am);
    ap = fmaf(a, bf2f(vp[(size_t)s*HDIM+h]), ap);
  }
  nmag[(size_t)n*HDIM+h]=am; nph[(size_t)n*HDIM+h]=ap;
}

// ---------------- message passing aggregation (gate precomputed) ----------------
__global__ __launch_bounds__(256) void k_mp_agg(const int* __restrict__ rowptr, const int* __restrict__ perm,
                         const int* __restrict__ src, const u16* __restrict__ gate,
                         const float* __restrict__ nmag, const float* __restrict__ nph,
                         u16* __restrict__ aggm, u16* __restrict__ aggp){
  int n = blockIdx.x; int h = threadIdx.x;
  int b = rowptr[n], e = rowptr[n+1];
  float am=0.f, ap=0.f;
  for(int i=b;i<e;i++){
    int ed=perm[i]; int s=src[ed];
    float g = bf2f(gate[(size_t)ed*HDIM+h]);
    am = fmaf(g, nmag[(size_t)s*HDIM+h], am);
    ap = fmaf(g, nph[(size_t)s*HDIM+h], ap);
  }
  aggm[(size_t)n*HDIM+h]=f2bf(am); aggp[(size_t)n*HDIM+h]=f2bf(ap);
}

// ---------------- residual + LayerNorm ----------------
__global__ __launch_bounds__(256) void k_resid_ln(const float* __restrict__ nmag, const float* __restrict__ nph,
                           float* __restrict__ mag, float* __restrict__ ph,
                           u16* __restrict__ magb, u16* __restrict__ phb,
                           const float* __restrict__ g, const float* __restrict__ b){
  int n = blockIdx.x, tid = threadIdx.x;
  size_t idx = (size_t)n*HDIM+tid;
  float t = nmag[idx] + mag[idx];
  float s1=t, s2=t*t;
  #pragma unroll
  for(int off=32; off; off>>=1){ s1 += __shfl_down(s1,off,64); s2 += __shfl_down(s2,off,64); }
  __shared__ float w1[4], w2[4], bc[2];
  int wid = tid>>6, lane = tid&63;
  if(lane==0){ w1[wid]=s1; w2[wid]=s2; }
  __syncthreads();
  if(tid==0){
    float a=w1[0]+w1[1]+w1[2]+w1[3];
    float q=w2[0]+w2[1]+w2[2]+w2[3];
    float mu = a*(1.f/HDIM);
    float var = q*(1.f/HDIM) - mu*mu;
    bc[0]=mu; bc[1]=rsqrtf(var+1e-5f);
  }
  __syncthreads();
  float mu=bc[0], rs=bc[1];
  float ln = (t-mu)*rs*g[tid]+b[tid];
  mag[idx] = ln; magb[idx] = f2bf(ln);
  float p2 = nph[idx] + ph[idx];
  ph[idx] = p2; phb[idx] = f2bf(p2);
}

// ---------------- projection input ----------------
__global__ void k_tcos(const float* __restrict__ mag, const float* __restrict__ ph,
                       u16* __restrict__ t){
  size_t i = (size_t)blockIdx.x*256+threadIdx.x;
  t[i] = f2bf(mag[i]*cosf(ph[i]));
}

// ---------------- pooling ----------------
__global__ void k_pool(const float* __restrict__ arepr, const int* __restrict__ n2m,
                       float* __restrict__ spool, float* __restrict__ cntf){
  int gid = blockIdx.x*256+threadIdx.x;
  int n = gid>>8, h = gid&255;
  int m = n2m[n];
  atomicAdd(&spool[(size_t)m*HDIM+h], arepr[(size_t)n*HDIM+h]);
  if(h==0) atomicAdd(&cntf[m], 1.f);
}

// ---------------- head MLP ----------------
__global__ __launch_bounds__(256) void k_head(const float* __restrict__ spool, const float* __restrict__ cntf,
                       const float* __restrict__ W1, const float* __restrict__ b1,
                       const float* __restrict__ W2, const float* __restrict__ b2,
                       const float* __restrict__ W3, const float* __restrict__ b3,
                       float* __restrict__ out){
  __shared__ float smol[2*HDIM];
  __shared__ float sh1[HDIM];
  __shared__ float sh2[HDIM/2];
  int m = blockIdx.x, tid = threadIdx.x;
  float sv = spool[(size_t)m*HDIM+tid];
  float c = cntf[m];
  smol[tid] = sv/fmaxf(c,1.f);
  smol[HDIM+tid] = sv;
  __syncthreads();
  float a = b1[tid];
  for(int i=0;i<2*HDIM;i++) a = fmaf(smol[i], W1[i*HDIM+tid], a);
  sh1[tid] = siluf(a);
  __syncthreads();
  if(tid<128){
    float a2 = b2[tid];
    for(int i=0;i<HDIM;i++) a2 = fmaf(sh1[i], W2[i*128+tid], a2);
    sh2[tid] = siluf(a2);
  }
  __syncthreads();
  if(tid<64){
    float p = sh2[tid]*W3[tid] + sh2[tid+64]*W3[tid+64];
    #pragma unroll
    for(int off=32; off; off>>=1) p += __shfl_down(p,off,64);
    if(tid==0) out[m] = p + b3[0];
  }
}

extern "C" void kernel_launch(void* const* d_in, const int* in_sizes, int n_in,
                              void* d_out, int out_size, void* d_ws, size_t ws_size,
                              hipStream_t stream){
  const float* atom_types = (const float*)d_in[0];
  const float* coords     = (const float*)d_in[1];
  const float* edge_dist  = (const float*)d_in[2];
  const int*   edge_index = (const int*)d_in[3];
  const int*   node2mol   = (const int*)d_in[4];
  const float* emb_Wm = (const float*)d_in[5];
  const float* emb_bm = (const float*)d_in[6];
  const float* emb_Wp = (const float*)d_in[7];
  const float* emb_bp = (const float*)d_in[8];
  const float* attn_Wqm = (const float*)d_in[9];
  const float* attn_Wkm = (const float*)d_in[10];
  const float* attn_Wvm = (const float*)d_in[11];
  const float* attn_Wqp = (const float*)d_in[12];
  const float* attn_Wkp = (const float*)d_in[13];
  const float* attn_Wvp = (const float*)d_in[14];
  const float* attn_We  = (const float*)d_in[15];
  const float* attn_be  = (const float*)d_in[16];
  const float* mp_We = (const float*)d_in[17];
  const float* mp_be = (const float*)d_in[18];
  const float* mp_Wm = (const float*)d_in[19];
  const float* mp_bm = (const float*)d_in[20];
  const float* mp_Wp = (const float*)d_in[21];
  const float* mp_bp = (const float*)d_in[22];
  const float* ln_g = (const float*)d_in[23];
  const float* ln_b = (const float*)d_in[24];
  const float* proj_W = (const float*)d_in[25];
  const float* proj_b = (const float*)d_in[26];
  const float* head_W1 = (const float*)d_in[27];
  const float* head_b1 = (const float*)d_in[28];
  const float* head_W2 = (const float*)d_in[29];
  const float* head_b2 = (const float*)d_in[30];
  const float* head_W3 = (const float*)d_in[31];
  const float* head_b3 = (const float*)d_in[32];
  float* out = (float*)d_out;

  float* ws = (float*)d_ws;
  const size_t NH = (size_t)N_NODES*HDIM;
  size_t o = 0;
  float* mag = ws + o; o += NH;
  float* ph  = ws + o; o += NH;
  float* nmag= ws + o; o += NH;
  float* nph = ws + o; o += NH;
  float* score = ws + o; o += N_EDGES;
  float* spool = ws + o; o += (size_t)N_MOLS*HDIM;
  float* cntf  = ws + o; o += N_MOLS;
  int* rowptr = (int*)(ws + o); o += N_NODES+1;
  int* cnt    = (int*)(ws + o); o += N_NODES;
  int* cursor = (int*)(ws + o); o += N_NODES;
  int* perm   = (int*)(ws + o); o += N_EDGES + 1;  // +1 keeps next offset 8B-aligned
  u16* magb = (u16*)(ws + o); o += NH/2;
  u16* phb  = (u16*)(ws + o); o += NH/2;
  u16* aggmb= (u16*)(ws + o); o += NH/2;
  u16* aggpb= (u16*)(ws + o); o += NH/2;
  u16* rbfb = (u16*)(ws + o); o += (size_t)N_EDGES*32;       // [E][64] bf16
  u16* arena= (u16*)(ws + o); o += (size_t)N_EDGES*128;      // gate [E][256] bf16 / qkv
  u16* wt   = (u16*)(ws + o); o += (25*(size_t)HH + 3*HDIM*64)/2;
  // arena aliases: qkv live between QKV gemm and attn_agg; gate live after.
  u16* qmb = arena + 0*NH; u16* kmb = arena + 1*NH; u16* vmb = arena + 2*NH;
  u16* qpb = arena + 3*NH; u16* kpb = arena + 4*NH; u16* vpb = arena + 5*NH;
  u16* gateb = arena;
  float* arepr = nmag;   // free after last resid_ln
  u16* tcosb = aggmb;    // free after last mp gemm

  const int* src = edge_index;
  const int* dst = edge_index + N_EDGES;

  // ---- weight convert/transpose descriptors ----
  WArgs wa;
  for(int l=0;l<NLAYER;l++){
    const float* srcs[6] = {attn_Wqm+(size_t)l*HH, attn_Wkm+(size_t)l*HH, attn_Wvm+(size_t)l*HH,
                            attn_Wqp+(size_t)l*HH, attn_Wkp+(size_t)l*HH, attn_Wvp+(size_t)l*HH};
    for(int j=0;j<6;j++){ wa.d[l*6+j] = { srcs[j], wt + (size_t)(l*6+j)*HH, HDIM, HDIM }; }
    wa.d[18+l] = { mp_Wm+(size_t)l*HH, wt + (size_t)(18+l)*HH, HDIM, HDIM };
    wa.d[21+l] = { mp_Wp+(size_t)l*HH, wt + (size_t)(21+l)*HH, HDIM, HDIM };
    wa.d[25+l] = { mp_We+(size_t)l*NRBF*HDIM, wt + (size_t)25*HH + (size_t)l*HDIM*64, NRBF, 64 };
  }
  wa.d[24] = { proj_W, wt + (size_t)24*HH, HDIM, HDIM };

  hipMemsetAsync(cnt, 0, N_NODES*sizeof(int), stream);
  k_hist<<<N_EDGES/256,256,0,stream>>>(dst, cnt);
  k_scan<<<1,1024,0,stream>>>(cnt, rowptr, cursor);
  k_scatter<<<N_EDGES/256,256,0,stream>>>(dst, cursor, perm);
  k_wconv<<<dim3(28,64),256,0,stream>>>(wa);
  k_rbf<<<(N_EDGES*64)/256,256,0,stream>>>(edge_dist, rbfb);
  k_embed<<<N_NODES,256,0,stream>>>(atom_types, coords, emb_Wm, emb_bm, emb_Wp, emb_bp,
                                    mag, ph, magb, phb);

  dim3 gn(HDIM/64, N_NODES/128);       // node gemms: (4, 128)
  dim3 ge(HDIM/64, N_EDGES/128);       // gate gemm: (4, 1024)
  for(int l=0;l<NLAYER;l++){
    QkvArgs qa;
    u16* outs[6] = {qmb, kmb, vmb, qpb, kpb, vpb};
    for(int j=0;j<6;j++){ qa.Wt[j] = wt + (size_t)(l*6+j)*HH; qa.out[j] = outs[j]; }
    k_gemm_qkv<<<dim3(4,128,6),256,0,stream>>>(magb, phb, qa);
    k_score<<<N_EDGES/4,256,0,stream>>>(qmb,kmb,qpb,kpb, rbfb, attn_We+(size_t)l*NRBF, attn_be+l,
                                        src, dst, score);
    k_segsoftmax<<<N_NODES/256,256,0,stream>>>(rowptr, perm, score);
    k_attn_agg<<<N_NODES,256,0,stream>>>(rowptr, perm, src, score, vmb, vpb, nmag, nph);
    k_gemm_gate<<<ge,256,0,stream>>>(rbfb, wt + (size_t)25*HH + (size_t)l*HDIM*64,
                                     mp_be+(size_t)l*HDIM, gateb);
    k_mp_agg<<<N_NODES,256,0,stream>>>(rowptr, perm, src, gateb, nmag, nph, aggmb, aggpb);
    k_gemm_mp<<<gn,256,0,stream>>>(aggmb, wt + (size_t)(18+l)*HH, mp_bm+(size_t)l*HDIM, nmag);
    k_gemm_mp<<<gn,256,0,stream>>>(aggpb, wt + (size_t)(21+l)*HH, mp_bp+(size_t)l*HDIM, nph);
    k_resid_ln<<<N_NODES,256,0,stream>>>(nmag, nph, mag, ph, magb, phb,
                                         ln_g+(size_t)l*HDIM, ln_b+(size_t)l*HDIM);
  }
  k_tcos<<<NH/256,256,0,stream>>>(mag, ph, tcosb);
  k_gemm_proj<<<gn,256,0,stream>>>(tcosb, wt + (size_t)24*HH, proj_b, arepr);
  hipMemsetAsync(spool, 0, ((size_t)N_MOLS*HDIM+N_MOLS)*sizeof(float), stream);
  k_pool<<<NH/256,256,0,stream>>>(arepr, node2mol, spool, cntf);
  k_head<<<N_MOLS,256,0,stream>>>(spool, cntf, head_W1, head_b1, head_W2, head_b2, head_W3, head_b3, out);
}

// Round 5
// 1002.307 us; speedup vs baseline: 1.9805x; 1.2307x over previous
//
#include <hip/hip_runtime.h>
#include <math.h>

#define N_NODES 16384
#define N_EDGES 131072
#define N_MOLS 512
#define HDIM 256
#define NLAYER 3
#define NRBF 50
#define CUT 5.0f
#define HH (HDIM*HDIM)

typedef unsigned short u16;
typedef __attribute__((ext_vector_type(8))) short short8v;
typedef __attribute__((ext_vector_type(4))) float f32x4;
typedef __attribute__((ext_vector_type(4))) unsigned short u16x4;

__device__ __forceinline__ float softplusf(float x){ return fmaxf(x,0.f)+log1pf(expf(-fabsf(x))); }
__device__ __forceinline__ float siluf(float x){ return x/(1.f+expf(-x)); }
__device__ __forceinline__ float bf2f(u16 u){ union{unsigned int i; float f;}v; v.i=((unsigned int)u)<<16; return v.f; }
__device__ __forceinline__ u16 f2bf(float f){ union{float f; unsigned int i;}v; v.f=f; unsigned int r = v.i + 0x7FFFu + ((v.i>>16)&1u); return (u16)(r>>16); }

__device__ __forceinline__ void gload_lds16(const void* g, void* l){
  __builtin_amdgcn_global_load_lds((const __attribute__((address_space(1))) unsigned int*)g,
                                   (__attribute__((address_space(3))) unsigned int*)l, 16, 0, 0);
}

// ---------------- CSR build ----------------
__global__ void k_hist(const int* __restrict__ dst, int* __restrict__ cnt){
  int e = blockIdx.x*256 + threadIdx.x;
  if(e < N_EDGES) atomicAdd(&cnt[dst[e]], 1);
}

__global__ __launch_bounds__(1024) void k_scan(const int* __restrict__ cnt,
                                               int* __restrict__ rowptr,
                                               int* __restrict__ cursor){
  __shared__ int part[1024];
  int tid = threadIdx.x;
  int base = tid*16;
  int loc[16]; int s=0;
  #pragma unroll
  for(int i=0;i<16;i++){ loc[i]=s; s+=cnt[base+i]; }
  part[tid]=s; __syncthreads();
  for(int off=1; off<1024; off<<=1){
    int v = (tid>=off)? part[tid-off] : 0;
    __syncthreads();
    part[tid] += v;
    __syncthreads();
  }
  int pre = (tid==0)?0:part[tid-1];
  #pragma unroll
  for(int i=0;i<16;i++){ int v = pre+loc[i]; rowptr[base+i]=v; cursor[base+i]=v; }
  if(tid==1023) rowptr[N_NODES]=part[1023];
}

__global__ void k_scatter(const int* __restrict__ dst, int* __restrict__ cursor,
                          int* __restrict__ perm){
  int e = blockIdx.x*256+threadIdx.x;
  if(e<N_EDGES){ int p = atomicAdd(&cursor[dst[e]],1); perm[p]=e; }
}

// ---------------- RBF (bf16, padded to 64) ----------------
__global__ void k_rbf(const float* __restrict__ dist, u16* __restrict__ rbf){
  int gid = blockIdx.x*256+threadIdx.x;
  int e = gid>>6, r = gid&63;
  u16 o = 0;
  if(r<NRBF){
    float d = dist[e];
    float env = 0.5f*(cosf(3.14159265358979f*d/CUT)+1.f) * (d<CUT ? 1.f:0.f);
    float c = CUT*(float)r/(float)(NRBF-1);
    float u = (d - c)/(CUT/(float)NRBF);
    o = f2bf(expf(-0.5f*u*u)*env);
  }
  rbf[(size_t)e*64+r] = o;
}

// ---------------- weight transpose+convert: W[K][256] f32 -> Wt[256][dK] bf16 ----------------
struct WDesc { const float* src; u16* dst; int K; int dK; };
struct WArgs { WDesc d[28]; };
__global__ __launch_bounds__(256) void k_wconv(WArgs a){
  WDesc w = a.d[blockIdx.x];
  int t = blockIdx.y;
  int ky = t >> 3, nx = t & 7;
  if(ky*32 >= w.dK) return;
  __shared__ float tile[32][33];
  int tid = threadIdx.x;
  int kk = tid >> 3, n4 = (tid & 7)*4;
  int k = ky*32 + kk;
  float4 v = {0.f,0.f,0.f,0.f};
  if(k < w.K) v = *(const float4*)(w.src + (size_t)k*HDIM + nx*32 + n4);
  tile[kk][n4+0]=v.x; tile[kk][n4+1]=v.y; tile[kk][n4+2]=v.z; tile[kk][n4+3]=v.w;
  __syncthreads();
  int nn = tid >> 3, k4 = (tid & 7)*4;
  u16x4 o;
  #pragma unroll
  for(int j=0;j<4;j++) o[j] = f2bf(tile[k4+j][nn]);
  *(u16x4*)(w.dst + (size_t)(nx*32+nn)*w.dK + ky*32 + k4) = o;
}

// ---------------- embedding ----------------
__global__ void k_embed(const float* __restrict__ at, const float* __restrict__ co,
                        const float* __restrict__ Wm, const float* __restrict__ bm,
                        const float* __restrict__ Wp, const float* __restrict__ bp,
                        float* __restrict__ mag, float* __restrict__ ph,
                        u16* __restrict__ magb, u16* __restrict__ phb){
  int n = blockIdx.x; int h = threadIdx.x;
  __shared__ float x[8];
  if(threadIdx.x<5) x[threadIdx.x] = at[n*5+threadIdx.x];
  else if(threadIdx.x<8) x[threadIdx.x] = co[n*3+threadIdx.x-5];
  __syncthreads();
  float tm=bm[h], tp=bp[h];
  #pragma unroll
  for(int i=0;i<8;i++){ tm = fmaf(x[i],Wm[i*HDIM+h],tm); tp = fmaf(x[i],Wp[i*HDIM+h],tp); }
  size_t idx = (size_t)n*HDIM+h;
  float m = softplusf(tm);
  float p = 3.14159265358979f*tanhf(tp);
  mag[idx]=m; ph[idx]=p; magb[idx]=f2bf(m); phb[idx]=f2bf(p);
}

// ---------------- MFMA GEMM body: C[M,256] = A[M,K]bf16 @ Bt[256,K]bf16^T ----------------
// BM=128, BN=64, BK=64; 256 threads = 4 waves in 2(M)x2(N); wave tile 64x32.
// MODE 0: bf16 out. 1: silu(x+bias)->bf16. 2: f32 += x+bias. 3: f32 = x+bias.
template<int MODE>
__device__ __forceinline__ void gemm_body(const u16* __restrict__ A,
                                          const u16* __restrict__ Bt,
                                          const float* __restrict__ bias,
                                          void* __restrict__ outp, int K){
  __shared__ __align__(16) u16 As[128*64];
  __shared__ __align__(16) u16 Bs[64*64];
  int tid = threadIdx.x;
  int lane = tid & 63, wid = tid >> 6;
  int wm = wid & 1, wn = wid >> 1;
  int m0 = blockIdx.y * 128;
  int n0 = blockIdx.x * 64;
  const size_t Kb = (size_t)K*2;
  f32x4 acc[4][2] = {};
  for(int k0=0; k0<K; k0+=64){
    #pragma unroll
    for(int it=0; it<4; it++){
      int off = it*4096 + tid*16;
      int row = off >> 7, col = off & 127;
      const char* g = (const char*)A + (size_t)(m0+row)*Kb + (size_t)k0*2 + col;
      gload_lds16(g, (char*)As + it*4096 + wid*1024);
    }
    #pragma unroll
    for(int it=0; it<2; it++){
      int off = it*4096 + tid*16;
      int row = off >> 7, col = off & 127;
      const char* g = (const char*)Bt + (size_t)(n0+row)*Kb + (size_t)k0*2 + col;
      gload_lds16(g, (char*)Bs + it*4096 + wid*1024);
    }
    __syncthreads();
    #pragma unroll
    for(int ks=0; ks<2; ks++){
      int kl = ks*32 + (lane>>4)*8;
      short8v a[4], b[2];
      #pragma unroll
      for(int fm=0; fm<4; fm++){
        int m = wm*64 + fm*16 + (lane&15);
        a[fm] = *(const short8v*)&As[m*64 + kl];
      }
      #pragma unroll
      for(int fn=0; fn<2; fn++){
        int n = wn*32 + fn*16 + (lane&15);
        b[fn] = *(const short8v*)&Bs[n*64 + kl];
      }
      #pragma unroll
      for(int fm=0; fm<4; fm++)
        #pragma unroll
        for(int fn=0; fn<2; fn++)
          acc[fm][fn] = __builtin_amdgcn_mfma_f32_16x16x32_bf16(a[fm], b[fn], acc[fm][fn], 0,0,0);
    }
    __syncthreads();
  }
  int ro = (lane>>4)*4, co = lane&15;
  #pragma unroll
  for(int fm=0; fm<4; fm++){
    #pragma unroll
    for(int fn=0; fn<2; fn++){
      int col = n0 + wn*32 + fn*16 + co;
      float bv = (MODE!=0) ? bias[col] : 0.f;
      #pragma unroll
      for(int r=0; r<4; r++){
        int row = m0 + wm*64 + fm*16 + ro + r;
        float v = acc[fm][fn][r] + bv;
        size_t ci = (size_t)row*HDIM + col;
        if(MODE==0) ((u16*)outp)[ci] = f2bf(v);
        else if(MODE==1) ((u16*)outp)[ci] = f2bf(siluf(v));
        else if(MODE==2) ((float*)outp)[ci] += v;
        else ((float*)outp)[ci] = v;
      }
    }
  }
}

struct QkvArgs { const u16* Wt[6]; u16* out[6]; };
__global__ __launch_bounds__(256,2) void k_gemm_qkv(const u16* __restrict__ magb,
                                                    const u16* __restrict__ phb, QkvArgs q){
  int z = blockIdx.z;
  const u16* A = (z<3) ? magb : phb;
  gemm_body<0>(A, q.Wt[z], nullptr, q.out[z], HDIM);
}
__global__ __launch_bounds__(256,2) void k_gemm_gate(const u16* __restrict__ rbfb,
                                                     const u16* __restrict__ Wt,
                                                     const float* __restrict__ be,
                                                     u16* __restrict__ gate){
  gemm_body<1>(rbfb, Wt, be, gate, 64);
}
struct MpArgs { const u16* A[2]; const u16* Wt[2]; const float* b[2]; float* C[2]; };
__global__ __launch_bounds__(256,2) void k_gemm_mp(MpArgs a){
  int z = blockIdx.z;
  gemm_body<2>(a.A[z], a.Wt[z], a.b[z], a.C[z], HDIM);
}
__global__ __launch_bounds__(256,2) void k_gemm_proj(const u16* __restrict__ Ab,
                                                     const u16* __restrict__ Wt,
                                                     const float* __restrict__ b,
                                                     float* __restrict__ C){
  gemm_body<3>(Ab, Wt, b, C, HDIM);
}

// ---------------- fused attention: score + online segment-softmax + V-aggregate ----------------
// one wave per dst node (4 nodes per 256-thread block); lane owns h = lane*4..lane*4+3
__global__ __launch_bounds__(256) void k_attn_fused(
    const int* __restrict__ rowptr, const int* __restrict__ perm,
    const int* __restrict__ src,
    const u16* __restrict__ qm, const u16* __restrict__ km,
    const u16* __restrict__ qp, const u16* __restrict__ kp,
    const u16* __restrict__ vm, const u16* __restrict__ vp,
    const u16* __restrict__ rbf, const float* __restrict__ We,
    const float* __restrict__ be,
    float* __restrict__ nmag, float* __restrict__ nph,
    u16* __restrict__ nmagb, u16* __restrict__ nphb)
{
  int wid = threadIdx.x >> 6, lane = threadIdx.x & 63;
  int d = blockIdx.x*4 + wid;
  int b = rowptr[d], e = rowptr[d+1];
  size_t qoff = (size_t)d*HDIM + lane*4;
  u16x4 qmv = *(const u16x4*)(qm + qoff);
  u16x4 qpv = *(const u16x4*)(qp + qoff);
  float qm4[4], qp4[4];
  #pragma unroll
  for(int j=0;j<4;j++){ qm4[j]=bf2f(qmv[j]); qp4[j]=bf2f(qpv[j]); }
  float Wel = (lane<NRBF) ? We[lane] : 0.f;
  float be0 = be[0];
  float m = -3.4e38f, z = 0.f;
  float avm[4] = {0.f,0.f,0.f,0.f}, avp[4] = {0.f,0.f,0.f,0.f};
  for(int i=b;i<e;i++){
    int ed = perm[i]; int s = src[ed];
    size_t ko = (size_t)s*HDIM + lane*4;
    u16x4 kmv = *(const u16x4*)(km + ko);
    u16x4 kpv = *(const u16x4*)(kp + ko);
    u16x4 vmv = *(const u16x4*)(vm + ko);
    u16x4 vpv = *(const u16x4*)(vp + ko);
    float rb = (lane<NRBF) ? bf2f(rbf[(size_t)ed*64+lane]) : 0.f;
    float p = 0.f;
    #pragma unroll
    for(int j=0;j<4;j++)
      p = fmaf(qm4[j]*bf2f(kmv[j]), __cosf(qp4[j]-bf2f(kpv[j])), p);
    p = fmaf(rb, Wel, p*0.0625f);
    #pragma unroll
    for(int off=32; off; off>>=1) p += __shfl_xor(p, off, 64);
    float sc = p + be0;
    float mn = fmaxf(m, sc);
    float scale = __expf(m - mn);
    float w = __expf(sc - mn);
    z = fmaf(z, scale, w);
    #pragma unroll
    for(int j=0;j<4;j++){
      avm[j] = fmaf(avm[j], scale, w*bf2f(vmv[j]));
      avp[j] = fmaf(avp[j], scale, w*bf2f(vpv[j]));
    }
    m = mn;
  }
  float inv = 1.f/(z + 1e-9f);
  float4 om, op; u16x4 omb, opb;
  float vo[4], po[4];
  #pragma unroll
  for(int j=0;j<4;j++){ vo[j]=avm[j]*inv; po[j]=avp[j]*inv; omb[j]=f2bf(vo[j]); opb[j]=f2bf(po[j]); }
  om.x=vo[0]; om.y=vo[1]; om.z=vo[2]; om.w=vo[3];
  op.x=po[0]; op.y=po[1]; op.z=po[2]; op.w=po[3];
  *(float4*)(nmag + qoff) = om;
  *(float4*)(nph + qoff) = op;
  *(u16x4*)(nmagb + qoff) = omb;
  *(u16x4*)(nphb + qoff) = opb;
}

// ---------------- message passing aggregation (gate precomputed, bf16 gathers) ----------------
__global__ __launch_bounds__(256) void k_mp_agg(const int* __restrict__ rowptr, const int* __restrict__ perm,
                         const int* __restrict__ src, const u16* __restrict__ gate,
                         const u16* __restrict__ nmagb, const u16* __restrict__ nphb,
                         u16* __restrict__ aggm, u16* __restrict__ aggp){
  int wid = threadIdx.x >> 6, lane = threadIdx.x & 63;
  int n = blockIdx.x*4 + wid;
  int b = rowptr[n], e = rowptr[n+1];
  float am[4]={0.f,0.f,0.f,0.f}, ap[4]={0.f,0.f,0.f,0.f};
  for(int i=b;i<e;i++){
    int ed = perm[i]; int s = src[ed];
    u16x4 gv = *(const u16x4*)(gate + (size_t)ed*HDIM + lane*4);
    u16x4 mv = *(const u16x4*)(nmagb + (size_t)s*HDIM + lane*4);
    u16x4 pv = *(const u16x4*)(nphb + (size_t)s*HDIM + lane*4);
    #pragma unroll
    for(int j=0;j<4;j++){
      float g = bf2f(gv[j]);
      am[j] = fmaf(g, bf2f(mv[j]), am[j]);
      ap[j] = fmaf(g, bf2f(pv[j]), ap[j]);
    }
  }
  u16x4 amb, apb;
  #pragma unroll
  for(int j=0;j<4;j++){ amb[j]=f2bf(am[j]); apb[j]=f2bf(ap[j]); }
  size_t o = (size_t)n*HDIM + lane*4;
  *(u16x4*)(aggm + o) = amb;
  *(u16x4*)(aggp + o) = apb;
}

// ---------------- residual + LayerNorm ----------------
__global__ __launch_bounds__(256) void k_resid_ln(const float* __restrict__ nmag, const float* __restrict__ nph,
                           float* __restrict__ mag, float* __restrict__ ph,
                           u16* __restrict__ magb, u16* __restrict__ phb,
                           const float* __restrict__ g, const float* __restrict__ b){
  int n = blockIdx.x, tid = threadIdx.x;
  size_t idx = (size_t)n*HDIM+tid;
  float t = nmag[idx] + mag[idx];
  float s1=t, s2=t*t;
  #pragma unroll
  for(int off=32; off; off>>=1){ s1 += __shfl_down(s1,off,64); s2 += __shfl_down(s2,off,64); }
  __shared__ float w1[4], w2[4], bc[2];
  int wid = tid>>6, lane = tid&63;
  if(lane==0){ w1[wid]=s1; w2[wid]=s2; }
  __syncthreads();
  if(tid==0){
    float a=w1[0]+w1[1]+w1[2]+w1[3];
    float q=w2[0]+w2[1]+w2[2]+w2[3];
    float mu = a*(1.f/HDIM);
    float var = q*(1.f/HDIM) - mu*mu;
    bc[0]=mu; bc[1]=rsqrtf(var+1e-5f);
  }
  __syncthreads();
  float mu=bc[0], rs=bc[1];
  float ln = (t-mu)*rs*g[tid]+b[tid];
  mag[idx] = ln; magb[idx] = f2bf(ln);
  float p2 = nph[idx] + ph[idx];
  ph[idx] = p2; phb[idx] = f2bf(p2);
}

// ---------------- projection input ----------------
__global__ void k_tcos(const float* __restrict__ mag, const float* __restrict__ ph,
                       u16* __restrict__ t){
  size_t i = (size_t)blockIdx.x*256+threadIdx.x;
  t[i] = f2bf(mag[i]*cosf(ph[i]));
}

// ---------------- pooling ----------------
__global__ void k_pool(const float* __restrict__ arepr, const int* __restrict__ n2m,
                       float* __restrict__ spool, float* __restrict__ cntf){
  int gid = blockIdx.x*256+threadIdx.x;
  int n = gid>>8, h = gid&255;
  int m = n2m[n];
  atomicAdd(&spool[(size_t)m*HDIM+h], arepr[(size_t)n*HDIM+h]);
  if(h==0) atomicAdd(&cntf[m], 1.f);
}

// ---------------- head MLP ----------------
__global__ __launch_bounds__(256) void k_head(const float* __restrict__ spool, const float* __restrict__ cntf,
                       const float* __restrict__ W1, const float* __restrict__ b1,
                       const float* __restrict__ W2, const float* __restrict__ b2,
                       const float* __restrict__ W3, const float* __restrict__ b3,
                       float* __restrict__ out){
  __shared__ float smol[2*HDIM];
  __shared__ float sh1[HDIM];
  __shared__ float sh2[HDIM/2];
  int m = blockIdx.x, tid = threadIdx.x;
  float sv = spool[(size_t)m*HDIM+tid];
  float c = cntf[m];
  smol[tid] = sv/fmaxf(c,1.f);
  smol[HDIM+tid] = sv;
  __syncthreads();
  float a = b1[tid];
  for(int i=0;i<2*HDIM;i++) a = fmaf(smol[i], W1[i*HDIM+tid], a);
  sh1[tid] = siluf(a);
  __syncthreads();
  if(tid<128){
    float a2 = b2[tid];
    for(int i=0;i<HDIM;i++) a2 = fmaf(sh1[i], W2[i*128+tid], a2);
    sh2[tid] = siluf(a2);
  }
  __syncthreads();
  if(tid<64){
    float p = sh2[tid]*W3[tid] + sh2[tid+64]*W3[tid+64];
    #pragma unroll
    for(int off=32; off; off>>=1) p += __shfl_down(p,off,64);
    if(tid==0) out[m] = p + b3[0];
  }
}

extern "C" void kernel_launch(void* const* d_in, const int* in_sizes, int n_in,
                              void* d_out, int out_size, void* d_ws, size_t ws_size,
                              hipStream_t stream){
  const float* atom_types = (const float*)d_in[0];
  const float* coords     = (const float*)d_in[1];
  const float* edge_dist  = (const float*)d_in[2];
  const int*   edge_index = (const int*)d_in[3];
  const int*   node2mol   = (const int*)d_in[4];
  const float* emb_Wm = (const float*)d_in[5];
  const float* emb_bm = (const float*)d_in[6];
  const float* emb_Wp = (const float*)d_in[7];
  const float* emb_bp = (const float*)d_in[8];
  const float* attn_Wqm = (const float*)d_in[9];
  const float* attn_Wkm = (const float*)d_in[10];
  const float* attn_Wvm = (const float*)d_in[11];
  const float* attn_Wqp = (const float*)d_in[12];
  const float* attn_Wkp = (const float*)d_in[13];
  const float* attn_Wvp = (const float*)d_in[14];
  const float* attn_We  = (const float*)d_in[15];
  const float* attn_be  = (const float*)d_in[16];
  const float* mp_We = (const float*)d_in[17];
  const float* mp_be = (const float*)d_in[18];
  const float* mp_Wm = (const float*)d_in[19];
  const float* mp_bm = (const float*)d_in[20];
  const float* mp_Wp = (const float*)d_in[21];
  const float* mp_bp = (const float*)d_in[22];
  const float* ln_g = (const float*)d_in[23];
  const float* ln_b = (const float*)d_in[24];
  const float* proj_W = (const float*)d_in[25];
  const float* proj_b = (const float*)d_in[26];
  const float* head_W1 = (const float*)d_in[27];
  const float* head_b1 = (const float*)d_in[28];
  const float* head_W2 = (const float*)d_in[29];
  const float* head_b2 = (const float*)d_in[30];
  const float* head_W3 = (const float*)d_in[31];
  const float* head_b3 = (const float*)d_in[32];
  float* out = (float*)d_out;

  float* ws = (float*)d_ws;
  const size_t NH = (size_t)N_NODES*HDIM;
  size_t o = 0;
  float* mag = ws + o; o += NH;
  float* ph  = ws + o; o += NH;
  float* nmag= ws + o; o += NH;
  float* nph = ws + o; o += NH;
  float* spool = ws + o; o += (size_t)N_MOLS*HDIM;
  float* cntf  = ws + o; o += N_MOLS;
  int* rowptr = (int*)(ws + o); o += N_NODES+1;
  int* cnt    = (int*)(ws + o); o += N_NODES;
  int* cursor = (int*)(ws + o); o += N_NODES;
  int* perm   = (int*)(ws + o); o += N_EDGES + 1;  // +1 keeps next offset 8B-aligned
  u16* magb = (u16*)(ws + o); o += NH/2;
  u16* phb  = (u16*)(ws + o); o += NH/2;
  u16* aggmb= (u16*)(ws + o); o += NH/2;
  u16* aggpb= (u16*)(ws + o); o += NH/2;
  u16* nmagb= (u16*)(ws + o); o += NH/2;
  u16* nphb = (u16*)(ws + o); o += NH/2;
  u16* rbfb = (u16*)(ws + o); o += (size_t)N_EDGES*32;       // [E][64] bf16
  u16* arena= (u16*)(ws + o); o += (size_t)N_EDGES*128;      // gate [E][256] bf16 / qkv
  u16* wt   = (u16*)(ws + o); o += (25*(size_t)HH + 3*HDIM*64)/2;
  // arena aliases: qkv live between QKV gemm and attn_fused; gate live after.
  u16* qmb = arena + 0*NH; u16* kmb = arena + 1*NH; u16* vmb = arena + 2*NH;
  u16* qpb = arena + 3*NH; u16* kpb = arena + 4*NH; u16* vpb = arena + 5*NH;
  u16* gateb = arena;
  float* arepr = nmag;   // free after last resid_ln
  u16* tcosb = aggmb;    // free after last mp gemm

  const int* src = edge_index;
  const int* dst = edge_index + N_EDGES;

  // ---- weight convert/transpose descriptors ----
  WArgs wa;
  for(int l=0;l<NLAYER;l++){
    const float* srcs[6] = {attn_Wqm+(size_t)l*HH, attn_Wkm+(size_t)l*HH, attn_Wvm+(size_t)l*HH,
                            attn_Wqp+(size_t)l*HH, attn_Wkp+(size_t)l*HH, attn_Wvp+(size_t)l*HH};
    for(int j=0;j<6;j++){ wa.d[l*6+j] = { srcs[j], wt + (size_t)(l*6+j)*HH, HDIM, HDIM }; }
    wa.d[18+l] = { mp_Wm+(size_t)l*HH, wt + (size_t)(18+l)*HH, HDIM, HDIM };
    wa.d[21+l] = { mp_Wp+(size_t)l*HH, wt + (size_t)(21+l)*HH, HDIM, HDIM };
    wa.d[25+l] = { mp_We+(size_t)l*NRBF*HDIM, wt + (size_t)25*HH + (size_t)l*HDIM*64, NRBF, 64 };
  }
  wa.d[24] = { proj_W, wt + (size_t)24*HH, HDIM, HDIM };

  hipMemsetAsync(cnt, 0, N_NODES*sizeof(int), stream);
  k_hist<<<N_EDGES/256,256,0,stream>>>(dst, cnt);
  k_scan<<<1,1024,0,stream>>>(cnt, rowptr, cursor);
  k_scatter<<<N_EDGES/256,256,0,stream>>>(dst, cursor, perm);
  k_wconv<<<dim3(28,64),256,0,stream>>>(wa);
  k_rbf<<<(N_EDGES*64)/256,256,0,stream>>>(edge_dist, rbfb);
  k_embed<<<N_NODES,256,0,stream>>>(atom_types, coords, emb_Wm, emb_bm, emb_Wp, emb_bp,
                                    mag, ph, magb, phb);

  dim3 gn(HDIM/64, N_NODES/128);       // node gemms: (4, 128)
  dim3 ge(HDIM/64, N_EDGES/128);       // gate gemm: (4, 1024)
  for(int l=0;l<NLAYER;l++){
    QkvArgs qa;
    u16* outs[6] = {qmb, kmb, vmb, qpb, kpb, vpb};
    for(int j=0;j<6;j++){ qa.Wt[j] = wt + (size_t)(l*6+j)*HH; qa.out[j] = outs[j]; }
    k_gemm_qkv<<<dim3(4,128,6),256,0,stream>>>(magb, phb, qa);
    k_attn_fused<<<N_NODES/4,256,0,stream>>>(rowptr, perm, src,
                                             qmb, kmb, qpb, kpb, vmb, vpb,
                                             rbfb, attn_We+(size_t)l*NRBF, attn_be+l,
                                             nmag, nph, nmagb, nphb);
    k_gemm_gate<<<ge,256,0,stream>>>(rbfb, wt + (size_t)25*HH + (size_t)l*HDIM*64,
                                     mp_be+(size_t)l*HDIM, gateb);
    k_mp_agg<<<N_NODES/4,256,0,stream>>>(rowptr, perm, src, gateb, nmagb, nphb, aggmb, aggpb);
    MpArgs ma;
    ma.A[0]=aggmb; ma.A[1]=aggpb;
    ma.Wt[0]=wt + (size_t)(18+l)*HH; ma.Wt[1]=wt + (size_t)(21+l)*HH;
    ma.b[0]=mp_bm+(size_t)l*HDIM; ma.b[1]=mp_bp+(size_t)l*HDIM;
    ma.C[0]=nmag; ma.C[1]=nph;
    k_gemm_mp<<<dim3(4,128,2),256,0,stream>>>(ma);
    k_resid_ln<<<N_NODES,256,0,stream>>>(nmag, nph, mag, ph, magb, phb,
                                         ln_g+(size_t)l*HDIM, ln_b+(size_t)l*HDIM);
  }
  k_tcos<<<NH/256,256,0,stream>>>(mag, ph, tcosb);
  k_gemm_proj<<<gn,256,0,stream>>>(tcosb, wt + (size_t)24*HH, proj_b, arepr);
  hipMemsetAsync(spool, 0, ((size_t)N_MOLS*HDIM+N_MOLS)*sizeof(float), stream);
  k_pool<<<NH/256,256,0,stream>>>(arepr, node2mol, spool, cntf);
  k_head<<<N_MOLS,256,0,stream>>>(spool, cntf, head_W1, head_b1, head_W2, head_b2, head_W3, head_b3, out);
}

// Round 6
// 943.609 us; speedup vs baseline: 2.1037x; 1.0622x over previous
//
#include <hip/hip_runtime.h>
#include <math.h>

#define N_NODES 16384
#define N_EDGES 131072
#define N_MOLS 512
#define HDIM 256
#define NLAYER 3
#define NRBF 50
#define CUT 5.0f
#define HH (HDIM*HDIM)

typedef unsigned short u16;
typedef __attribute__((ext_vector_type(8))) short short8v;
typedef __attribute__((ext_vector_type(4))) float f32x4;
typedef __attribute__((ext_vector_type(4))) unsigned short u16x4;
typedef __attribute__((ext_vector_type(8))) unsigned short u16x8;
typedef __attribute__((ext_vector_type(2))) unsigned short u16x2;

__device__ __forceinline__ float softplusf(float x){ return fmaxf(x,0.f)+log1pf(expf(-fabsf(x))); }
__device__ __forceinline__ float siluf(float x){ return x/(1.f+expf(-x)); }
__device__ __forceinline__ float bf2f(u16 u){ union{unsigned int i; float f;}v; v.i=((unsigned int)u)<<16; return v.f; }
__device__ __forceinline__ u16 f2bf(float f){ union{float f; unsigned int i;}v; v.f=f; unsigned int r = v.i + 0x7FFFu + ((v.i>>16)&1u); return (u16)(r>>16); }

__device__ __forceinline__ void gload_lds16(const void* g, void* l){
  __builtin_amdgcn_global_load_lds((const __attribute__((address_space(1))) unsigned int*)g,
                                   (__attribute__((address_space(3))) unsigned int*)l, 16, 0, 0);
}

// ---------------- CSR build ----------------
__global__ void k_hist(const int* __restrict__ dst, int* __restrict__ cnt){
  int e = blockIdx.x*256 + threadIdx.x;
  if(e < N_EDGES) atomicAdd(&cnt[dst[e]], 1);
}

__global__ __launch_bounds__(1024) void k_scan(const int* __restrict__ cnt,
                                               int* __restrict__ rowptr,
                                               int* __restrict__ cursor){
  __shared__ int part[1024];
  int tid = threadIdx.x;
  int base = tid*16;
  int loc[16]; int s=0;
  #pragma unroll
  for(int i=0;i<16;i++){ loc[i]=s; s+=cnt[base+i]; }
  part[tid]=s; __syncthreads();
  for(int off=1; off<1024; off<<=1){
    int v = (tid>=off)? part[tid-off] : 0;
    __syncthreads();
    part[tid] += v;
    __syncthreads();
  }
  int pre = (tid==0)?0:part[tid-1];
  #pragma unroll
  for(int i=0;i<16;i++){ int v = pre+loc[i]; rowptr[base+i]=v; cursor[base+i]=v; }
  if(tid==1023) rowptr[N_NODES]=part[1023];
}

__global__ void k_scatter(const int* __restrict__ dst, int* __restrict__ cursor,
                          int* __restrict__ perm){
  int e = blockIdx.x*256+threadIdx.x;
  if(e<N_EDGES){ int p = atomicAdd(&cursor[dst[e]],1); perm[p]=e; }
}

// ---------------- RBF (bf16, padded to 64) ----------------
__global__ void k_rbf(const float* __restrict__ dist, u16* __restrict__ rbf){
  int gid = blockIdx.x*256+threadIdx.x;
  int e = gid>>6, r = gid&63;
  u16 o = 0;
  if(r<NRBF){
    float d = dist[e];
    float env = 0.5f*(cosf(3.14159265358979f*d/CUT)+1.f) * (d<CUT ? 1.f:0.f);
    float c = CUT*(float)r/(float)(NRBF-1);
    float u = (d - c)/(CUT/(float)NRBF);
    o = f2bf(expf(-0.5f*u*u)*env);
  }
  rbf[(size_t)e*64+r] = o;
}

// ---------------- weight transpose+convert: W[K][256] f32 -> Wt[256][dK] bf16 ----------------
struct WDesc { const float* src; u16* dst; int K; int dK; };
struct WArgs { WDesc d[28]; };
__global__ __launch_bounds__(256) void k_wconv(WArgs a){
  WDesc w = a.d[blockIdx.x];
  int t = blockIdx.y;
  int ky = t >> 3, nx = t & 7;
  if(ky*32 >= w.dK) return;
  __shared__ float tile[32][33];
  int tid = threadIdx.x;
  int kk = tid >> 3, n4 = (tid & 7)*4;
  int k = ky*32 + kk;
  float4 v = {0.f,0.f,0.f,0.f};
  if(k < w.K) v = *(const float4*)(w.src + (size_t)k*HDIM + nx*32 + n4);
  tile[kk][n4+0]=v.x; tile[kk][n4+1]=v.y; tile[kk][n4+2]=v.z; tile[kk][n4+3]=v.w;
  __syncthreads();
  int nn = tid >> 3, k4 = (tid & 7)*4;
  u16x4 o;
  #pragma unroll
  for(int j=0;j<4;j++) o[j] = f2bf(tile[k4+j][nn]);
  *(u16x4*)(w.dst + (size_t)(nx*32+nn)*w.dK + ky*32 + k4) = o;
}

// ---------------- embedding ----------------
__global__ void k_embed(const float* __restrict__ at, const float* __restrict__ co,
                        const float* __restrict__ Wm, const float* __restrict__ bm,
                        const float* __restrict__ Wp, const float* __restrict__ bp,
                        float* __restrict__ mag, float* __restrict__ ph,
                        u16* __restrict__ magb, u16* __restrict__ phb){
  int n = blockIdx.x; int h = threadIdx.x;
  __shared__ float x[8];
  if(threadIdx.x<5) x[threadIdx.x] = at[n*5+threadIdx.x];
  else if(threadIdx.x<8) x[threadIdx.x] = co[n*3+threadIdx.x-5];
  __syncthreads();
  float tm=bm[h], tp=bp[h];
  #pragma unroll
  for(int i=0;i<8;i++){ tm = fmaf(x[i],Wm[i*HDIM+h],tm); tp = fmaf(x[i],Wp[i*HDIM+h],tp); }
  size_t idx = (size_t)n*HDIM+h;
  float m = softplusf(tm);
  float p = 3.14159265358979f*tanhf(tp);
  mag[idx]=m; ph[idx]=p; magb[idx]=f2bf(m); phb[idx]=f2bf(p);
}

// ---------------- MFMA GEMM body: C[M,ostr..] = A[M,K]bf16 @ Bt[256,K]bf16^T ----------------
// BM=128, BN=64, BK=64; 256 threads = 4 waves in 2(M)x2(N); wave tile 64x32.
// MODE 0: bf16 out. 1: silu(x+bias)->bf16. 2: f32 += x+bias. 3: f32 = x+bias.
template<int MODE>
__device__ __forceinline__ void gemm_body(const u16* __restrict__ A,
                                          const u16* __restrict__ Bt,
                                          const float* __restrict__ bias,
                                          void* __restrict__ outp, int K, int ostr){
  __shared__ __align__(16) u16 As[128*64];
  __shared__ __align__(16) u16 Bs[64*64];
  int tid = threadIdx.x;
  int lane = tid & 63, wid = tid >> 6;
  int wm = wid & 1, wn = wid >> 1;
  int m0 = blockIdx.y * 128;
  int n0 = blockIdx.x * 64;
  const size_t Kb = (size_t)K*2;
  f32x4 acc[4][2] = {};
  for(int k0=0; k0<K; k0+=64){
    #pragma unroll
    for(int it=0; it<4; it++){
      int off = it*4096 + tid*16;
      int row = off >> 7, col = off & 127;
      const char* g = (const char*)A + (size_t)(m0+row)*Kb + (size_t)k0*2 + col;
      gload_lds16(g, (char*)As + it*4096 + wid*1024);
    }
    #pragma unroll
    for(int it=0; it<2; it++){
      int off = it*4096 + tid*16;
      int row = off >> 7, col = off & 127;
      const char* g = (const char*)Bt + (size_t)(n0+row)*Kb + (size_t)k0*2 + col;
      gload_lds16(g, (char*)Bs + it*4096 + wid*1024);
    }
    __syncthreads();
    #pragma unroll
    for(int ks=0; ks<2; ks++){
      int kl = ks*32 + (lane>>4)*8;
      short8v a[4], b[2];
      #pragma unroll
      for(int fm=0; fm<4; fm++){
        int m = wm*64 + fm*16 + (lane&15);
        a[fm] = *(const short8v*)&As[m*64 + kl];
      }
      #pragma unroll
      for(int fn=0; fn<2; fn++){
        int n = wn*32 + fn*16 + (lane&15);
        b[fn] = *(const short8v*)&Bs[n*64 + kl];
      }
      #pragma unroll
      for(int fm=0; fm<4; fm++)
        #pragma unroll
        for(int fn=0; fn<2; fn++)
          acc[fm][fn] = __builtin_amdgcn_mfma_f32_16x16x32_bf16(a[fm], b[fn], acc[fm][fn], 0,0,0);
    }
    __syncthreads();
  }
  int ro = (lane>>4)*4, co = lane&15;
  #pragma unroll
  for(int fm=0; fm<4; fm++){
    #pragma unroll
    for(int fn=0; fn<2; fn++){
      int col = n0 + wn*32 + fn*16 + co;
      float bv = (MODE!=0) ? bias[col] : 0.f;
      #pragma unroll
      for(int r=0; r<4; r++){
        int row = m0 + wm*64 + fm*16 + ro + r;
        float v = acc[fm][fn][r] + bv;
        size_t ci = (size_t)row*ostr + col;
        if(MODE==0) ((u16*)outp)[ci] = f2bf(v);
        else if(MODE==1) ((u16*)outp)[ci] = f2bf(siluf(v));
        else if(MODE==2) ((float*)outp)[ci] += v;
        else ((float*)outp)[ci] = v;
      }
    }
  }
}

// qkv pack layout per node (u16): [qm:0, qp:256, km:512, kp:768, vm:1024, vp:1280], stride 1536
struct QkvArgs { const u16* Wt[6]; u16* out[6]; };
__global__ __launch_bounds__(256,2) void k_gemm_qkv(const u16* __restrict__ magb,
                                                    const u16* __restrict__ phb, QkvArgs q){
  int z = blockIdx.z;
  const u16* A = (z<3) ? magb : phb;
  gemm_body<0>(A, q.Wt[z], nullptr, q.out[z], HDIM, 1536);
}
__global__ __launch_bounds__(256,2) void k_gemm_gate(const u16* __restrict__ rbfb,
                                                     const u16* __restrict__ Wt,
                                                     const float* __restrict__ be,
                                                     u16* __restrict__ gate){
  gemm_body<1>(rbfb, Wt, be, gate, 64, 256);
}
struct MpArgs { const u16* A[2]; const u16* Wt[2]; const float* b[2]; float* C[2]; };
__global__ __launch_bounds__(256,2) void k_gemm_mp(MpArgs a){
  int z = blockIdx.z;
  gemm_body<2>(a.A[z], a.Wt[z], a.b[z], a.C[z], HDIM, 256);
}
__global__ __launch_bounds__(256,2) void k_gemm_proj(const u16* __restrict__ Ab,
                                                     const u16* __restrict__ Wt,
                                                     const float* __restrict__ b,
                                                     float* __restrict__ C){
  gemm_body<3>(Ab, Wt, b, C, HDIM, 256);
}

// ---------------- fused attention v2: 2 edges per wave (32 lanes each), no max-shift ----------------
// wave per dst node; half-wave owns alternate edges; lane owns 8 channels (u16x8).
__global__ __launch_bounds__(256) void k_attn_fused(
    const int* __restrict__ rowptr, const int* __restrict__ perm,
    const int* __restrict__ src,
    const u16* __restrict__ pack, const u16* __restrict__ rbf,
    const float* __restrict__ We, const float* __restrict__ be,
    float* __restrict__ nmag, float* __restrict__ nph,
    u16* __restrict__ npack)
{
  int wid = threadIdx.x >> 6, lane = threadIdx.x & 63;
  int hid = lane >> 5, l = lane & 31;
  int d = blockIdx.x*4 + wid;
  int b = rowptr[d], e = rowptr[d+1];
  const u16* qb = pack + (size_t)d*1536 + l*8;
  u16x8 qm8 = *(const u16x8*)qb;
  u16x8 qp8 = *(const u16x8*)(qb + 256);
  float qmf[8], qpf[8];
  #pragma unroll
  for(int j=0;j<8;j++){ qmf[j]=bf2f(qm8[j]); qpf[j]=bf2f(qp8[j]); }
  float We0 = (2*l   < NRBF) ? We[2*l]   : 0.f;
  float We1 = (2*l+1 < NRBF) ? We[2*l+1] : 0.f;
  float be0 = be[0];
  float z = 0.f;
  float avm[8] = {0,0,0,0,0,0,0,0}, avp[8] = {0,0,0,0,0,0,0,0};
  for(int i = b + hid; i < e; i += 2){
    int ed = perm[i]; int s = src[ed];
    const u16* kb = pack + (size_t)s*1536 + l*8;
    u16x8 km8 = *(const u16x8*)(kb + 512);
    u16x8 kp8 = *(const u16x8*)(kb + 768);
    u16x8 vm8 = *(const u16x8*)(kb + 1024);
    u16x8 vp8 = *(const u16x8*)(kb + 1280);
    u16x2 rb2 = *(const u16x2*)(rbf + (size_t)ed*64 + 2*l);
    float p = 0.f;
    #pragma unroll
    for(int j=0;j<8;j++)
      p = fmaf(qmf[j]*bf2f(km8[j]), __cosf(qpf[j]-bf2f(kp8[j])), p);
    float t = fmaf(bf2f(rb2[0]), We0, fmaf(bf2f(rb2[1]), We1, p*0.0625f));
    #pragma unroll
    for(int off=16; off; off>>=1) t += __shfl_xor(t, off, 64);
    float w = __expf(t + be0);   // scores are O(1): no max-shift needed (softmax shift-invariant)
    z += w;
    #pragma unroll
    for(int j=0;j<8;j++){
      avm[j] = fmaf(w, bf2f(vm8[j]), avm[j]);
      avp[j] = fmaf(w, bf2f(vp8[j]), avp[j]);
    }
  }
  z += __shfl_xor(z, 32, 64);
  #pragma unroll
  for(int j=0;j<8;j++){
    avm[j] += __shfl_xor(avm[j], 32, 64);
    avp[j] += __shfl_xor(avp[j], 32, 64);
  }
  if(hid==0){
    float inv = 1.f/(z + 1e-9f);
    u16x8 mb, pb;
    #pragma unroll
    for(int j=0;j<8;j++){ avm[j]*=inv; avp[j]*=inv; mb[j]=f2bf(avm[j]); pb[j]=f2bf(avp[j]); }
    size_t no = (size_t)d*256 + l*8;
    *(float4*)(nmag + no)     = make_float4(avm[0],avm[1],avm[2],avm[3]);
    *(float4*)(nmag + no + 4) = make_float4(avm[4],avm[5],avm[6],avm[7]);
    *(float4*)(nph + no)      = make_float4(avp[0],avp[1],avp[2],avp[3]);
    *(float4*)(nph + no + 4)  = make_float4(avp[4],avp[5],avp[6],avp[7]);
    u16* nb = npack + (size_t)d*512 + l*8;
    *(u16x8*)nb = mb;
    *(u16x8*)(nb + 256) = pb;
  }
}

// ---------------- message passing aggregation v2 (2 edges/wave, packed bf16 gathers) ----------------
__global__ __launch_bounds__(256) void k_mp_agg(const int* __restrict__ rowptr, const int* __restrict__ perm,
                         const int* __restrict__ src, const u16* __restrict__ gate,
                         const u16* __restrict__ npack,
                         u16* __restrict__ aggm, u16* __restrict__ aggp){
  int wid = threadIdx.x >> 6, lane = threadIdx.x & 63;
  int hid = lane >> 5, l = lane & 31;
  int n = blockIdx.x*4 + wid;
  int b = rowptr[n], e = rowptr[n+1];
  float am[8] = {0,0,0,0,0,0,0,0}, ap[8] = {0,0,0,0,0,0,0,0};
  for(int i = b + hid; i < e; i += 2){
    int ed = perm[i]; int s = src[ed];
    u16x8 g8 = *(const u16x8*)(gate + (size_t)ed*256 + l*8);
    const u16* nb = npack + (size_t)s*512 + l*8;
    u16x8 m8 = *(const u16x8*)nb;
    u16x8 p8 = *(const u16x8*)(nb + 256);
    #pragma unroll
    for(int j=0;j<8;j++){
      float g = bf2f(g8[j]);
      am[j] = fmaf(g, bf2f(m8[j]), am[j]);
      ap[j] = fmaf(g, bf2f(p8[j]), ap[j]);
    }
  }
  #pragma unroll
  for(int j=0;j<8;j++){
    am[j] += __shfl_xor(am[j], 32, 64);
    ap[j] += __shfl_xor(ap[j], 32, 64);
  }
  if(hid==0){
    u16x8 amb, apb;
    #pragma unroll
    for(int j=0;j<8;j++){ amb[j]=f2bf(am[j]); apb[j]=f2bf(ap[j]); }
    size_t o = (size_t)n*256 + l*8;
    *(u16x8*)(aggm + o) = amb;
    *(u16x8*)(aggp + o) = apb;
  }
}

// ---------------- residual + LayerNorm (LAST fuses mag*cos(ph) projection input) ----------------
template<int LAST>
__global__ __launch_bounds__(256) void k_resid_ln(const float* __restrict__ nmag, const float* __restrict__ nph,
                           float* __restrict__ mag, float* __restrict__ ph,
                           u16* __restrict__ magb, u16* __restrict__ phb,
                           u16* __restrict__ tcosb,
                           const float* __restrict__ g, const float* __restrict__ b){
  int n = blockIdx.x, tid = threadIdx.x;
  size_t idx = (size_t)n*HDIM+tid;
  float t = nmag[idx] + mag[idx];
  float s1=t, s2=t*t;
  #pragma unroll
  for(int off=32; off; off>>=1){ s1 += __shfl_down(s1,off,64); s2 += __shfl_down(s2,off,64); }
  __shared__ float w1[4], w2[4], bc[2];
  int wid = tid>>6, lane = tid&63;
  if(lane==0){ w1[wid]=s1; w2[wid]=s2; }
  __syncthreads();
  if(tid==0){
    float a=w1[0]+w1[1]+w1[2]+w1[3];
    float q=w2[0]+w2[1]+w2[2]+w2[3];
    float mu = a*(1.f/HDIM);
    float var = q*(1.f/HDIM) - mu*mu;
    bc[0]=mu; bc[1]=rsqrtf(var+1e-5f);
  }
  __syncthreads();
  float mu=bc[0], rs=bc[1];
  float ln = (t-mu)*rs*g[tid]+b[tid];
  float p2 = nph[idx] + ph[idx];
  if(LAST){
    tcosb[idx] = f2bf(ln*__cosf(p2));
  } else {
    mag[idx] = ln; magb[idx] = f2bf(ln);
    ph[idx] = p2; phb[idx] = f2bf(p2);
  }
}

// ---------------- pooling ----------------
__global__ void k_pool(const float* __restrict__ arepr, const int* __restrict__ n2m,
                       float* __restrict__ spool, float* __restrict__ cntf){
  int gid = blockIdx.x*256+threadIdx.x;
  int n = gid>>8, h = gid&255;
  int m = n2m[n];
  atomicAdd(&spool[(size_t)m*HDIM+h], arepr[(size_t)n*HDIM+h]);
  if(h==0) atomicAdd(&cntf[m], 1.f);
}

// ---------------- head MLP ----------------
__global__ __launch_bounds__(256) void k_head(const float* __restrict__ spool, const float* __restrict__ cntf,
                       const float* __restrict__ W1, const float* __restrict__ b1,
                       const float* __restrict__ W2, const float* __restrict__ b2,
                       const float* __restrict__ W3, const float* __restrict__ b3,
                       float* __restrict__ out){
  __shared__ float smol[2*HDIM];
  __shared__ float sh1[HDIM];
  __shared__ float sh2[HDIM/2];
  int m = blockIdx.x, tid = threadIdx.x;
  float sv = spool[(size_t)m*HDIM+tid];
  float c = cntf[m];
  smol[tid] = sv/fmaxf(c,1.f);
  smol[HDIM+tid] = sv;
  __syncthreads();
  float a = b1[tid];
  for(int i=0;i<2*HDIM;i++) a = fmaf(smol[i], W1[i*HDIM+tid], a);
  sh1[tid] = siluf(a);
  __syncthreads();
  if(tid<128){
    float a2 = b2[tid];
    for(int i=0;i<HDIM;i++) a2 = fmaf(sh1[i], W2[i*128+tid], a2);
    sh2[tid] = siluf(a2);
  }
  __syncthreads();
  if(tid<64){
    float p = sh2[tid]*W3[tid] + sh2[tid+64]*W3[tid+64];
    #pragma unroll
    for(int off=32; off; off>>=1) p += __shfl_down(p,off,64);
    if(tid==0) out[m] = p + b3[0];
  }
}

extern "C" void kernel_launch(void* const* d_in, const int* in_sizes, int n_in,
                              void* d_out, int out_size, void* d_ws, size_t ws_size,
                              hipStream_t stream){
  const float* atom_types = (const float*)d_in[0];
  const float* coords     = (const float*)d_in[1];
  const float* edge_dist  = (const float*)d_in[2];
  const int*   edge_index = (const int*)d_in[3];
  const int*   node2mol   = (const int*)d_in[4];
  const float* emb_Wm = (const float*)d_in[5];
  const float* emb_bm = (const float*)d_in[6];
  const float* emb_Wp = (const float*)d_in[7];
  const float* emb_bp = (const float*)d_in[8];
  const float* attn_Wqm = (const float*)d_in[9];
  const float* attn_Wkm = (const float*)d_in[10];
  const float* attn_Wvm = (const float*)d_in[11];
  const float* attn_Wqp = (const float*)d_in[12];
  const float* attn_Wkp = (const float*)d_in[13];
  const float* attn_Wvp = (const float*)d_in[14];
  const float* attn_We  = (const float*)d_in[15];
  const float* attn_be  = (const float*)d_in[16];
  const float* mp_We = (const float*)d_in[17];
  const float* mp_be = (const float*)d_in[18];
  const float* mp_Wm = (const float*)d_in[19];
  const float* mp_bm = (const float*)d_in[20];
  const float* mp_Wp = (const float*)d_in[21];
  const float* mp_bp = (const float*)d_in[22];
  const float* ln_g = (const float*)d_in[23];
  const float* ln_b = (const float*)d_in[24];
  const float* proj_W = (const float*)d_in[25];
  const float* proj_b = (const float*)d_in[26];
  const float* head_W1 = (const float*)d_in[27];
  const float* head_b1 = (const float*)d_in[28];
  const float* head_W2 = (const float*)d_in[29];
  const float* head_b2 = (const float*)d_in[30];
  const float* head_W3 = (const float*)d_in[31];
  const float* head_b3 = (const float*)d_in[32];
  float* out = (float*)d_out;

  float* ws = (float*)d_ws;
  const size_t NH = (size_t)N_NODES*HDIM;
  size_t o = 0;
  float* mag = ws + o; o += NH;
  float* ph  = ws + o; o += NH;
  float* nmag= ws + o; o += NH;
  float* nph = ws + o; o += NH;
  float* spool = ws + o; o += (size_t)N_MOLS*HDIM;
  float* cntf  = ws + o; o += N_MOLS;
  int* rowptr = (int*)(ws + o); o += N_NODES+1;
  int* cnt    = (int*)(ws + o); o += N_NODES;
  int* cursor = (int*)(ws + o); o += N_NODES;
  int* perm   = (int*)(ws + o); o += N_EDGES + 1;  // +1 keeps next offset 8B-aligned
  u16* magb = (u16*)(ws + o); o += NH/2;
  u16* phb  = (u16*)(ws + o); o += NH/2;
  u16* aggmb= (u16*)(ws + o); o += NH/2;
  u16* aggpb= (u16*)(ws + o); o += NH/2;
  u16* npack= (u16*)(ws + o); o += NH;                        // [N][2][256] bf16
  u16* rbfb = (u16*)(ws + o); o += (size_t)N_EDGES*32;        // [E][64] bf16
  u16* arena= (u16*)(ws + o); o += (size_t)N_EDGES*128;       // qkv pack [N][1536] / gate [E][256]
  u16* wt   = (u16*)(ws + o); o += (25*(size_t)HH + 3*HDIM*64)/2;
  u16* pack = arena;       // qkv: live qkv-gemm -> attn
  u16* gateb = arena;      // gate: live gate-gemm -> mp_agg (after pack dead)
  float* arepr = nmag;     // free after last resid_ln
  u16* tcosb = aggmb;      // free after last mp gemm

  const int* src = edge_index;
  const int* dst = edge_index + N_EDGES;

  // ---- weight convert/transpose descriptors ----
  WArgs wa;
  for(int l=0;l<NLAYER;l++){
    const float* srcs[6] = {attn_Wqm+(size_t)l*HH, attn_Wkm+(size_t)l*HH, attn_Wvm+(size_t)l*HH,
                            attn_Wqp+(size_t)l*HH, attn_Wkp+(size_t)l*HH, attn_Wvp+(size_t)l*HH};
    for(int j=0;j<6;j++){ wa.d[l*6+j] = { srcs[j], wt + (size_t)(l*6+j)*HH, HDIM, HDIM }; }
    wa.d[18+l] = { mp_Wm+(size_t)l*HH, wt + (size_t)(18+l)*HH, HDIM, HDIM };
    wa.d[21+l] = { mp_Wp+(size_t)l*HH, wt + (size_t)(21+l)*HH, HDIM, HDIM };
    wa.d[25+l] = { mp_We+(size_t)l*NRBF*HDIM, wt + (size_t)25*HH + (size_t)l*HDIM*64, NRBF, 64 };
  }
  wa.d[24] = { proj_W, wt + (size_t)24*HH, HDIM, HDIM };

  hipMemsetAsync(cnt, 0, N_NODES*sizeof(int), stream);
  k_hist<<<N_EDGES/256,256,0,stream>>>(dst, cnt);
  k_scan<<<1,1024,0,stream>>>(cnt, rowptr, cursor);
  k_scatter<<<N_EDGES/256,256,0,stream>>>(dst, cursor, perm);
  k_wconv<<<dim3(28,64),256,0,stream>>>(wa);
  k_rbf<<<(N_EDGES*64)/256,256,0,stream>>>(edge_dist, rbfb);
  k_embed<<<N_NODES,256,0,stream>>>(atom_types, coords, emb_Wm, emb_bm, emb_Wp, emb_bp,
                                    mag, ph, magb, phb);

  dim3 gn(HDIM/64, N_NODES/128);       // node gemms: (4, 128)
  dim3 ge(HDIM/64, N_EDGES/128);       // gate gemm: (4, 1024)
  for(int l=0;l<NLAYER;l++){
    QkvArgs qa;
    const int zoff[6] = {0, 512, 1024, 256, 768, 1280}; // qm,km,vm,qp,kp,vp
    for(int j=0;j<6;j++){ qa.Wt[j] = wt + (size_t)(l*6+j)*HH; qa.out[j] = pack + zoff[j]; }
    k_gemm_qkv<<<dim3(4,128,6),256,0,stream>>>(magb, phb, qa);
    k_attn_fused<<<N_NODES/4,256,0,stream>>>(rowptr, perm, src, pack,
                                             rbfb, attn_We+(size_t)l*NRBF, attn_be+l,
                                             nmag, nph, npack);
    k_gemm_gate<<<ge,256,0,stream>>>(rbfb, wt + (size_t)25*HH + (size_t)l*HDIM*64,
                                     mp_be+(size_t)l*HDIM, gateb);
    k_mp_agg<<<N_NODES/4,256,0,stream>>>(rowptr, perm, src, gateb, npack, aggmb, aggpb);
    MpArgs ma;
    ma.A[0]=aggmb; ma.A[1]=aggpb;
    ma.Wt[0]=wt + (size_t)(18+l)*HH; ma.Wt[1]=wt + (size_t)(21+l)*HH;
    ma.b[0]=mp_bm+(size_t)l*HDIM; ma.b[1]=mp_bp+(size_t)l*HDIM;
    ma.C[0]=nmag; ma.C[1]=nph;
    k_gemm_mp<<<dim3(4,128,2),256,0,stream>>>(ma);
    if(l < NLAYER-1)
      k_resid_ln<0><<<N_NODES,256,0,stream>>>(nmag, nph, mag, ph, magb, phb, nullptr,
                                              ln_g+(size_t)l*HDIM, ln_b+(size_t)l*HDIM);
    else
      k_resid_ln<1><<<N_NODES,256,0,stream>>>(nmag, nph, mag, ph, magb, phb, tcosb,
                                              ln_g+(size_t)l*HDIM, ln_b+(size_t)l*HDIM);
  }
  k_gemm_proj<<<gn,256,0,stream>>>(tcosb, wt + (size_t)24*HH, proj_b, arepr);
  hipMemsetAsync(spool, 0, ((size_t)N_MOLS*HDIM+N_MOLS)*sizeof(float), stream);
  k_pool<<<NH/256,256,0,stream>>>(arepr, node2mol, spool, cntf);
  k_head<<<N_MOLS,256,0,stream>>>(spool, cntf, head_W1, head_b1, head_W2, head_b2, head_W3, head_b3, out);
}